// Round 8
// baseline (250.437 us; speedup 1.0000x reference)
//
#include <hip/hip_runtime.h>

namespace {

constexpr int HW = 16384;   // pixels per image
constexpr int C  = 192;
constexpr int C3 = 576;
constexpr int CH = 48;
constexpr int K  = 192;

using bf16x8 = __attribute__((ext_vector_type(8))) short;
using f32x4  = __attribute__((ext_vector_type(4))) float;

__device__ inline unsigned short f2bf(float f) {
  unsigned u = __float_as_uint(f);
  unsigned r = (u + 0x7fff + ((u >> 16) & 1)) >> 16;
  return (unsigned short)r;
}
__device__ inline float bf2f(unsigned short b) {
  return __uint_as_float(((unsigned)b) << 16);
}

// async global->LDS, 16B per lane. LDS dest = wave-uniform base + lane*16.
__device__ __forceinline__ void ld_g2l16(const unsigned short* g, unsigned short* l) {
  __builtin_amdgcn_global_load_lds(
      (const __attribute__((address_space(1))) unsigned int*)(unsigned long long)(const void*)g,
      (__attribute__((address_space(3))) unsigned int*)(unsigned int)(unsigned long long)(void*)l,
      16, 0, 0);
}

// ---- split fp32 -> bf16 hi/lo (4 elems/thread), all images -----------------
__global__ __launch_bounds__(256) void cvt_split(const float* __restrict__ in,
                                                 unsigned short* __restrict__ hi,
                                                 unsigned short* __restrict__ lo) {
  const int t = blockIdx.x * 256 + threadIdx.x;
  const float4 v = ((const float4*)in)[t];
  const float vv[4] = {v.x, v.y, v.z, v.w};
  unsigned short h[4], l[4];
#pragma unroll
  for (int j = 0; j < 4; ++j) {
    h[j] = f2bf(vv[j]);
    l[j] = f2bf(vv[j] - bf2f(h[j]));
  }
  ((ushort4*)hi)[t] = make_ushort4(h[0], h[1], h[2], h[3]);
  ((ushort4*)lo)[t] = make_ushort4(l[0], l[1], l[2], l[3]);
}

// ---- transpose + split qkv weights: [192,576] -> hi/lo [576][192] ----------
__global__ __launch_bounds__(256) void cvt_wqkv(const float* __restrict__ wqkv,
                                                unsigned short* __restrict__ wqh,
                                                unsigned short* __restrict__ wql) {
  const int t = blockIdx.x * 256 + threadIdx.x;  // 0 .. 576*192-1
  const int n = t / 192;
  const int k = t % 192;
  const float v = wqkv[k * C3 + n];
  const unsigned short h = f2bf(v);
  wqh[n * 192 + k] = h;
  wql[n * 192 + k] = f2bf(v - bf2f(h));
}

// ---- MFMA GEMM: Co[M,N] = A[M,192] @ Bt[N,192]^T, 3-pass bf16 split --------
// Staging via global_load_lds (linear LDS dest, pre-swizzled source so the
// existing swizzled ds_read path is unchanged). One barrier per k-step.
template <int N, bool PERB>
__global__ __launch_bounds__(256, 3) void gemm_mfma(const unsigned short* __restrict__ Ah,
                                                    const unsigned short* __restrict__ Al,
                                                    const unsigned short* __restrict__ Bh,
                                                    const unsigned short* __restrict__ Bl,
                                                    float* __restrict__ Co) {
  __shared__ __align__(16) unsigned short sAh[2][128 * 32];
  __shared__ __align__(16) unsigned short sAl[2][128 * 32];
  __shared__ __align__(16) unsigned short sBh[2][64 * 32];
  __shared__ __align__(16) unsigned short sBl[2][64 * 32];
  const int t = threadIdx.x;
  const int lane = t & 63;
  const int wv = t >> 6;
  const int m0 = blockIdx.x * 128;
  const int n0 = blockIdx.y * 64;
  const size_t boff = PERB ? (size_t)(m0 >> 14) * (192 * 192) : 0;
  const int wr = wv >> 1, wc = wv & 1;
  const int fr_row = lane & 15;
  const int fr_swz = ((lane >> 4) ^ (lane & 3)) << 3;

  // staging geometry: LDS[row][phys_slot] = global[row][phys_slot ^ (row&3)]
  const int arow0 = wv * 32;           // A rows per wave: [wv*32, wv*32+32), 2 issues
  const int lrow  = lane >> 2;         // +0..15 within an issue
  const int lslot = lane & 3;          // phys 16B slot
  const int brow0 = wv * 16;           // B rows per wave: [wv*16, wv*16+16), 1 issue

  f32x4 acc[4][2] = {};

  auto stage = [&](int buf, int k0) {
#pragma unroll
    for (int r = 0; r < 2; ++r) {
      const int row = arow0 + r * 16 + lrow;
      const int ssl = lslot ^ (row & 3);
      const size_t go = (size_t)(m0 + row) * K + k0 + (ssl << 3);
      ld_g2l16(&Ah[go], &sAh[buf][(arow0 + r * 16) * 32]);
      ld_g2l16(&Al[go], &sAl[buf][(arow0 + r * 16) * 32]);
    }
    {
      const int row = brow0 + lrow;
      const int ssl = lslot ^ (row & 3);
      const size_t go = boff + (size_t)(n0 + row) * K + k0 + (ssl << 3);
      ld_g2l16(&Bh[go], &sBh[buf][brow0 * 32]);
      ld_g2l16(&Bl[go], &sBl[buf][brow0 * 32]);
    }
  };

  stage(0, 0);
  __syncthreads();
#pragma unroll
  for (int ks = 0; ks < 6; ++ks) {
    if (ks < 5) stage((ks + 1) & 1, (ks + 1) * 32);
    const int buf = ks & 1;
    bf16x8 fah[4], fal[4], fbh[2], fbl[2];
#pragma unroll
    for (int i = 0; i < 4; ++i) {
      const int row = wr * 64 + i * 16 + fr_row;
      fah[i] = *(const bf16x8*)&sAh[buf][row * 32 + fr_swz];
      fal[i] = *(const bf16x8*)&sAl[buf][row * 32 + fr_swz];
    }
#pragma unroll
    for (int j = 0; j < 2; ++j) {
      const int row = wc * 32 + j * 16 + fr_row;
      fbh[j] = *(const bf16x8*)&sBh[buf][row * 32 + fr_swz];
      fbl[j] = *(const bf16x8*)&sBl[buf][row * 32 + fr_swz];
    }
#pragma unroll
    for (int i = 0; i < 4; ++i)
#pragma unroll
      for (int j = 0; j < 2; ++j) {
        acc[i][j] = __builtin_amdgcn_mfma_f32_16x16x32_bf16(fah[i], fbh[j], acc[i][j], 0, 0, 0);
        acc[i][j] = __builtin_amdgcn_mfma_f32_16x16x32_bf16(fah[i], fbl[j], acc[i][j], 0, 0, 0);
        acc[i][j] = __builtin_amdgcn_mfma_f32_16x16x32_bf16(fal[i], fbh[j], acc[i][j], 0, 0, 0);
      }
    if (ks < 5) __syncthreads();
  }

  const int er = (lane >> 4) << 2;  // C/D: col=lane&15, row=(lane>>4)*4+reg
  const int ec = lane & 15;
#pragma unroll
  for (int i = 0; i < 4; ++i)
#pragma unroll
    for (int j = 0; j < 2; ++j) {
      float* cp = &Co[(size_t)(m0 + wr * 64 + i * 16 + er) * N + n0 + wc * 32 + j * 16 + ec];
#pragma unroll
      for (int r = 0; r < 4; ++r) cp[(size_t)r * N] = acc[i][j][r];
    }
}

// ---- depthwise 3x3 SAME, y-blocked x2 --------------------------------------
// q,k -> packed uint (hi | lo<<16) qkp[p][384]; v -> bf16 hi/lo [p][192]
__global__ __launch_bounds__(256) void dwconv3x3_v2(const float* __restrict__ in,
                                                    const float* __restrict__ wdw,
                                                    unsigned int* __restrict__ qkp,
                                                    unsigned short* __restrict__ vh,
                                                    unsigned short* __restrict__ vl) {
  const int t = blockIdx.x * 256 + threadIdx.x;
  const int c4 = t % 144;
  const int pix2 = t / 144;          // (img, y-pair, x)
  const int x = pix2 & 127;
  const int yp = (pix2 >> 7) & 63;
  const int img = pix2 >> 13;
  const int y0 = yp * 2;

  float4 wt[3][3];
#pragma unroll
  for (int i = 0; i < 3; ++i)
#pragma unroll
    for (int j = 0; j < 3; ++j)
      wt[i][j] = *(const float4*)&wdw[(size_t)(i * 3 + j) * C3 + c4 * 4];

  float4 tap[4][3];
  const bool interior = ((unsigned)(x - 1) < 126u) && ((unsigned)(yp - 1) < 62u);
  if (interior) {
    const float* base = &in[((size_t)(img << 14) + (y0 << 7) + x) * C3 + c4 * 4];
#pragma unroll
    for (int i = 0; i < 4; ++i)
#pragma unroll
      for (int j = 0; j < 3; ++j)
        tap[i][j] = *(const float4*)&base[(size_t)((i - 1) * 128 + (j - 1)) * C3];
  } else {
#pragma unroll
    for (int i = 0; i < 4; ++i) {
      const int ry = y0 - 1 + i;
      const int ryc = ry < 0 ? 0 : (ry > 127 ? 127 : ry);
      const bool vy = (unsigned)ry < 128u;
#pragma unroll
      for (int j = 0; j < 3; ++j) {
        const int rx = x - 1 + j;
        const int rxc = rx < 0 ? 0 : (rx > 127 ? 127 : rx);
        float4 v = *(const float4*)&in[((size_t)(img << 14) + (ryc << 7) + rxc) * C3 + c4 * 4];
        if (!(vy && ((unsigned)rx < 128u))) v = make_float4(0.f, 0.f, 0.f, 0.f);
        tap[i][j] = v;
      }
    }
  }

  float4 out0 = make_float4(0.f, 0.f, 0.f, 0.f);
  float4 out1 = make_float4(0.f, 0.f, 0.f, 0.f);
#pragma unroll
  for (int i = 0; i < 3; ++i)
#pragma unroll
    for (int j = 0; j < 3; ++j) {
      const float4 w = wt[i][j];
      const float4 a = tap[i][j];
      const float4 b = tap[i + 1][j];
      out0.x += a.x * w.x; out0.y += a.y * w.y; out0.z += a.z * w.z; out0.w += a.w * w.w;
      out1.x += b.x * w.x; out1.y += b.y * w.y; out1.z += b.z * w.z; out1.w += b.w * w.w;
    }

  const int p0 = (img << 14) + (y0 << 7) + x;
  const int p1 = p0 + 128;
  const float v0[4] = {out0.x, out0.y, out0.z, out0.w};
  const float v1[4] = {out1.x, out1.y, out1.z, out1.w};
  if (c4 < 96) {
    uint4 a, b;
    unsigned* ap = (unsigned*)&a;
    unsigned* bp = (unsigned*)&b;
#pragma unroll
    for (int j = 0; j < 4; ++j) {
      unsigned short h0 = f2bf(v0[j]);
      unsigned short l0 = f2bf(v0[j] - bf2f(h0));
      ap[j] = (unsigned)h0 | ((unsigned)l0 << 16);
      unsigned short h1 = f2bf(v1[j]);
      unsigned short l1 = f2bf(v1[j] - bf2f(h1));
      bp[j] = (unsigned)h1 | ((unsigned)l1 << 16);
    }
    *(uint4*)&qkp[(size_t)p0 * 384 + c4 * 4] = a;
    *(uint4*)&qkp[(size_t)p1 * 384 + c4 * 4] = b;
  } else {
    const int cc = (c4 - 96) * 4;
    ushort4 h0, l0, h1, l1;
    unsigned short *h0p = (unsigned short*)&h0, *l0p = (unsigned short*)&l0;
    unsigned short *h1p = (unsigned short*)&h1, *l1p = (unsigned short*)&l1;
#pragma unroll
    for (int j = 0; j < 4; ++j) {
      unsigned short hb = f2bf(v0[j]);
      h0p[j] = hb; l0p[j] = f2bf(v0[j] - bf2f(hb));
      hb = f2bf(v1[j]);
      h1p[j] = hb; l1p[j] = f2bf(v1[j] - bf2f(hb));
    }
    *(ushort4*)&vh[(size_t)p0 * 192 + cc] = h0;
    *(ushort4*)&vl[(size_t)p0 * 192 + cc] = l0;
    *(ushort4*)&vh[(size_t)p1 * 192 + cc] = h1;
    *(ushort4*)&vl[(size_t)p1 * 192 + cc] = l1;
  }
}

// ------- Gram v3 (MFMA): G = Q^T K per (img,h), 3-pass bf16; + ssq ----------
__global__ __launch_bounds__(256) void gram48_mfma(const unsigned int* __restrict__ qkp,
                                                   float* __restrict__ G,
                                                   float* __restrict__ ssqq,
                                                   float* __restrict__ ssqk) {
  constexpr int W = 50;
  __shared__ unsigned int smem[2 * 128 * W];   // sq | sk; reused as f32 reduce buf
  unsigned int* sq = smem;
  unsigned int* sk = smem + 128 * W;
  const int tid = threadIdx.x;
  const int lane = tid & 63;
  const int wv = tid >> 6;
  const int pair = blockIdx.y;          // img*4 + h  (img local to pass)
  const int img = pair >> 2, h = pair & 3;
  const int qcol = h * 48;
  const int kcol = 192 + h * 48;

  f32x4 acc[3][3] = {};
  float ssq_acc = 0.f;
  const int sch = tid % 96;
  const int shalf = tid / 96;

  for (int rnd = 0; rnd < 2; ++rnd) {
    const int sbase = (img << 14) + blockIdx.x * 256 + rnd * 128;
#pragma unroll
    for (int r = 0; r < 6; ++r) {
      const int idx = tid + (r << 8);    // 0..1535 = 128 rows x 12 uint4
      const int row = idx / 12, cc = (idx % 12) * 4;
      const uint4 vq = *(const uint4*)&qkp[(size_t)(sbase + row) * 384 + qcol + cc];
      const uint4 vk = *(const uint4*)&qkp[(size_t)(sbase + row) * 384 + kcol + cc];
      unsigned int* dq = &sq[row * W + cc];
      unsigned int* dk = &sk[row * W + cc];
      *(uint2*)dq = make_uint2(vq.x, vq.y);
      *(uint2*)(dq + 2) = make_uint2(vq.z, vq.w);
      *(uint2*)dk = make_uint2(vk.x, vk.y);
      *(uint2*)(dk + 2) = make_uint2(vk.z, vk.w);
    }
    __syncthreads();
    {
      const int s0 = wv * 32 + ((lane >> 4) << 3);
      const int cm = lane & 15;
      bf16x8 qh[3], ql[3], kh[3], kl[3];
#pragma unroll
      for (int t3 = 0; t3 < 3; ++t3) {
#pragma unroll
        for (int j = 0; j < 8; ++j) {
          const unsigned int uq = sq[(s0 + j) * W + t3 * 16 + cm];
          const unsigned int uk = sk[(s0 + j) * W + t3 * 16 + cm];
          qh[t3][j] = (short)(uq & 0xffffu);
          ql[t3][j] = (short)(uq >> 16);
          kh[t3][j] = (short)(uk & 0xffffu);
          kl[t3][j] = (short)(uk >> 16);
        }
      }
#pragma unroll
      for (int mt = 0; mt < 3; ++mt)
#pragma unroll
        for (int nt = 0; nt < 3; ++nt) {
          acc[mt][nt] = __builtin_amdgcn_mfma_f32_16x16x32_bf16(qh[mt], kh[nt], acc[mt][nt], 0, 0, 0);
          acc[mt][nt] = __builtin_amdgcn_mfma_f32_16x16x32_bf16(qh[mt], kl[nt], acc[mt][nt], 0, 0, 0);
          acc[mt][nt] = __builtin_amdgcn_mfma_f32_16x16x32_bf16(ql[mt], kh[nt], acc[mt][nt], 0, 0, 0);
        }
    }
    if (tid < 192) {
      const unsigned int* srcb = (sch < 48) ? &sq[sch] : &sk[sch - 48];
      const int sstart = shalf * 64;
#pragma unroll 4
      for (int s = 0; s < 64; ++s) {
        const unsigned int u = srcb[(size_t)(sstart + s) * W];
        const float v = bf2f((unsigned short)(u & 0xffffu)) + bf2f((unsigned short)(u >> 16));
        ssq_acc += v * v;
      }
    }
    __syncthreads();
  }

  float* red = (float*)smem;
  const int col = lane & 15;
  const int rbase = (lane >> 4) * 4;
#pragma unroll
  for (int mt = 0; mt < 3; ++mt)
#pragma unroll
    for (int nt = 0; nt < 3; ++nt)
#pragma unroll
      for (int rg = 0; rg < 4; ++rg)
        red[wv * 2304 + (mt * 16 + rbase + rg) * 48 + nt * 16 + col] = acc[mt][nt][rg];
  __syncthreads();
  float* Gm = &G[(size_t)pair * 2304];
#pragma unroll
  for (int c = 0; c < 9; ++c) {
    const int cell = tid + (c << 8);
    const float s4 = red[cell] + red[2304 + cell] + red[4608 + cell] + red[6912 + cell];
    atomicAdd(&Gm[cell], s4);
  }
  if (tid < 192) {
    if (sch < 48) atomicAdd(&ssqq[img * 192 + h * 48 + sch], ssq_acc);
    else          atomicAdd(&ssqk[img * 192 + h * 48 + sch - 48], ssq_acc);
  }
}

// ---- softmax over d of G*temp/(|q||k|), one wave per (img,h,row) -----------
__global__ __launch_bounds__(64) void attn_softmax(const float* __restrict__ G,
                                                   const float* __restrict__ ssqq,
                                                   const float* __restrict__ ssqk,
                                                   const float* __restrict__ temp,
                                                   float* __restrict__ attn) {
  const int r = blockIdx.x;          // 0..47
  const int h = blockIdx.y & 3;
  const int img = blockIdx.y >> 2;
  const int lane = threadIdx.x;
  const size_t base = (size_t)(img * 4 + h) * 2304;
  const float t = temp[h];
  const float qn = ssqq[img * 192 + h * CH + r];
  float val = -1e30f;
  if (lane < 48) {
    const float kn = ssqk[img * 192 + h * CH + lane];
    val = G[base + r * 48 + lane] * t * rsqrtf(qn * kn);
  }
  float m = val;
#pragma unroll
  for (int off = 32; off; off >>= 1) m = fmaxf(m, __shfl_xor(m, off));
  const float e = (lane < 48) ? expf(val - m) : 0.f;
  float ssum = e;
#pragma unroll
  for (int off = 32; off; off >>= 1) ssum += __shfl_xor(ssum, off);
  if (lane < 48) attn[base + r * 48 + lane] = e / ssum;
}

// ---- W_eff^T[img][n][D] = sum_c' A[img][h(D)][c'][D%48] * Wp[48h+c'][n] ----
__global__ __launch_bounds__(256) void make_weff(const float* __restrict__ attn,
                                                 const float* __restrict__ wproj,
                                                 unsigned short* __restrict__ weh,
                                                 unsigned short* __restrict__ wel) {
  const int t = blockIdx.x * 256 + threadIdx.x;   // over NI*192*192
  const int img = t / 36864;
  const int r = t % 36864;
  const int n = r / 192;
  const int D = r % 192;
  const int h = D / 48, dd = D % 48;
  const float* A = &attn[(size_t)(img * 4 + h) * 2304 + dd];
  const float* Wp = &wproj[(size_t)(h * 48) * 192 + n];
  float acc = 0.f;
#pragma unroll
  for (int c = 0; c < 48; ++c) acc += A[c * 48] * Wp[c * 192];
  const unsigned short hb = f2bf(acc);
  weh[(size_t)img * 36864 + n * 192 + D] = hb;
  wel[(size_t)img * 36864 + n * 192 + D] = f2bf(acc - bf2f(hb));
}

}  // namespace

extern "C" void kernel_launch(void* const* d_in, const int* in_sizes, int n_in,
                              void* d_out, int out_size, void* d_ws, size_t ws_size,
                              hipStream_t stream) {
  const float* x      = (const float*)d_in[0];
  const float* w_qkv  = (const float*)d_in[1];
  const float* w_dw   = (const float*)d_in[2];
  const float* w_proj = (const float*)d_in[3];
  const float* temp   = (const float*)d_in[4];
  float* out = (float*)d_out;

  // NI images per pass. NI=2 ≈ 203 MB (ws is 256 MiB), NI=1 ≈ 128 MB.
  auto layout_bytes = [](int NI) -> size_t {
    return (size_t)NI * HW * 576 * 4       // qkv fp32
         + (size_t)NI * HW * 384 * 4       // qkp packed uint (q,k hi|lo)
         + (size_t)NI * HW * 192 * 2 * 2   // vh, vl
         + (size_t)4 * HW * 192 * 2 * 2    // xh, xl (all 4 images)
         + 2 * 221184                      // wqh, wql
         + 153600                          // G, ssqq, ssqk (all 4 images)
         + 147456                          // attnb (all 4 images)
         + 2 * 294912;                     // weh, wel (all 4 images)
  };
  const int NI = (ws_size >= layout_bytes(2)) ? 2 : 1;
  const int npass = 4 / NI;
  const int npix = NI * HW;

  char* p = (char*)d_ws;
  float* qkv = (float*)p;            p += (size_t)npix * 576 * 4;
  unsigned int* qkp = (unsigned int*)p;     p += (size_t)npix * 384 * 4;
  unsigned short* vh = (unsigned short*)p;  p += (size_t)npix * 192 * 2;
  unsigned short* vl = (unsigned short*)p;  p += (size_t)npix * 192 * 2;
  unsigned short* xh = (unsigned short*)p;  p += (size_t)4 * HW * 192 * 2;
  unsigned short* xl = (unsigned short*)p;  p += (size_t)4 * HW * 192 * 2;
  unsigned short* wqh = (unsigned short*)p; p += 221184;
  unsigned short* wql = (unsigned short*)p; p += 221184;
  float* G    = (float*)p;           p += 147456;   // 16 (img,h) pairs
  float* ssqq = (float*)p;           p += 3072;     // 4 img x 192
  float* ssqk = (float*)p;           p += 3072;
  float* attnb = (float*)p;          p += 147456;
  unsigned short* weh = (unsigned short*)p; p += 294912;
  unsigned short* wel = (unsigned short*)p;

  cvt_wqkv<<<432, 256, 0, stream>>>(w_qkv, wqh, wql);
  cvt_split<<<4 * HW * 192 / 1024, 256, 0, stream>>>(x, xh, xl);
  hipMemsetAsync(G, 0, 153600, stream);  // G+ssqq+ssqk, all 4 images, once

  for (int pass = 0; pass < npass; ++pass) {
    const size_t arow = (size_t)pass * npix * 192;
    float* outb = out + (size_t)pass * npix * C;
    float* Gp    = G + (size_t)pass * NI * 4 * 2304;
    float* sqp   = ssqq + (size_t)pass * NI * 192;
    float* skp   = ssqk + (size_t)pass * NI * 192;
    float* ap    = attnb + (size_t)pass * NI * 4 * 2304;
    unsigned short* wehp = weh + (size_t)pass * NI * 36864;
    unsigned short* welp = wel + (size_t)pass * NI * 36864;
    gemm_mfma<576, false><<<dim3(npix / 128, 9), 256, 0, stream>>>(
        xh + arow, xl + arow, wqh, wql, qkv);
    dwconv3x3_v2<<<npix * 72 / 256, 256, 0, stream>>>(qkv, w_dw, qkp, vh, vl);
    gram48_mfma<<<dim3(64, 4 * NI), 256, 0, stream>>>(qkp, Gp, sqp, skp);
    attn_softmax<<<dim3(48, 4 * NI), 64, 0, stream>>>(Gp, sqp, skp, temp, ap);
    make_weff<<<NI * 144, 256, 0, stream>>>(ap, w_proj, wehp, welp);
    gemm_mfma<192, true><<<dim3(npix / 128, 3), 256, 0, stream>>>(
        vh, vl, wehp, welp, outb);
  }
}

// Round 9
// 204.239 us; speedup vs baseline: 1.2262x; 1.2262x over previous
//
#include <hip/hip_runtime.h>

namespace {

constexpr int HW = 16384;   // pixels per image
constexpr int C  = 192;
constexpr int C3 = 576;
constexpr int CH = 48;
constexpr int K  = 192;

using bf16x8 = __attribute__((ext_vector_type(8))) short;
using f32x4  = __attribute__((ext_vector_type(4))) float;

__device__ inline unsigned short f2bf(float f) {
  unsigned u = __float_as_uint(f);
  unsigned r = (u + 0x7fff + ((u >> 16) & 1)) >> 16;
  return (unsigned short)r;
}
__device__ inline float bf2f(unsigned short b) {
  return __uint_as_float(((unsigned)b) << 16);
}

// async global->LDS, 16B per lane. LDS dest = wave-uniform base + lane*16.
__device__ __forceinline__ void ld_g2l16(const unsigned short* g, unsigned short* l) {
  __builtin_amdgcn_global_load_lds(
      (const __attribute__((address_space(1))) unsigned int*)(unsigned long long)(const void*)g,
      (__attribute__((address_space(3))) unsigned int*)(unsigned int)(unsigned long long)(void*)l,
      16, 0, 0);
}

// ---- fp32 -> bf16 (hi only; 2-pass Markidis keeps lo only on the B side) ---
__global__ __launch_bounds__(256) void cvt_x(const float* __restrict__ in,
                                             unsigned short* __restrict__ hi) {
  const int t = blockIdx.x * 256 + threadIdx.x;
  const float4 v = ((const float4*)in)[t];
  ((ushort4*)hi)[t] = make_ushort4(f2bf(v.x), f2bf(v.y), f2bf(v.z), f2bf(v.w));
}

// ---- transpose + split qkv weights: [192,576] -> hi/lo [576][192] ----------
__global__ __launch_bounds__(256) void cvt_wqkv(const float* __restrict__ wqkv,
                                                unsigned short* __restrict__ wqh,
                                                unsigned short* __restrict__ wql) {
  const int t = blockIdx.x * 256 + threadIdx.x;  // 0 .. 576*192-1
  const int n = t / 192;
  const int k = t % 192;
  const float v = wqkv[k * C3 + n];
  const unsigned short h = f2bf(v);
  wqh[n * 192 + k] = h;
  wql[n * 192 + k] = f2bf(v - bf2f(h));
}

// ---- MFMA GEMM: Co[M,N] = Ah[M,192] @ (Bh+Bl)[N,192]^T, 2-pass bf16 --------
// Staging via global_load_lds (linear LDS dest, pre-swizzled source).
template <int N, bool PERB>
__global__ __launch_bounds__(256, 4) void gemm_mfma(const unsigned short* __restrict__ Ah,
                                                    const unsigned short* __restrict__ Bh,
                                                    const unsigned short* __restrict__ Bl,
                                                    float* __restrict__ Co) {
  __shared__ __align__(16) unsigned short sAh[2][128 * 32];
  __shared__ __align__(16) unsigned short sBh[2][64 * 32];
  __shared__ __align__(16) unsigned short sBl[2][64 * 32];
  const int t = threadIdx.x;
  const int lane = t & 63;
  const int wv = t >> 6;
  const int m0 = blockIdx.x * 128;
  const int n0 = blockIdx.y * 64;
  const size_t boff = PERB ? (size_t)(m0 >> 14) * (192 * 192) : 0;
  const int wr = wv >> 1, wc = wv & 1;
  const int fr_row = lane & 15;
  const int fr_swz = ((lane >> 4) ^ (lane & 3)) << 3;

  // staging geometry: LDS[row][phys_slot] = global[row][phys_slot ^ (row&3)]
  const int arow0 = wv * 32;           // A rows per wave: 2 issues of 16 rows
  const int lrow  = lane >> 2;
  const int lslot = lane & 3;
  const int brow0 = wv * 16;           // B rows per wave: 1 issue

  f32x4 acc[4][2] = {};

  auto stage = [&](int buf, int k0) {
#pragma unroll
    for (int r = 0; r < 2; ++r) {
      const int row = arow0 + r * 16 + lrow;
      const int ssl = lslot ^ (row & 3);
      const size_t go = (size_t)(m0 + row) * K + k0 + (ssl << 3);
      ld_g2l16(&Ah[go], &sAh[buf][(arow0 + r * 16) * 32]);
    }
    {
      const int row = brow0 + lrow;
      const int ssl = lslot ^ (row & 3);
      const size_t go = boff + (size_t)(n0 + row) * K + k0 + (ssl << 3);
      ld_g2l16(&Bh[go], &sBh[buf][brow0 * 32]);
      ld_g2l16(&Bl[go], &sBl[buf][brow0 * 32]);
    }
  };

  stage(0, 0);
  __syncthreads();
#pragma unroll
  for (int ks = 0; ks < 6; ++ks) {
    if (ks < 5) stage((ks + 1) & 1, (ks + 1) * 32);
    const int buf = ks & 1;
    bf16x8 fah[4], fbh[2], fbl[2];
#pragma unroll
    for (int i = 0; i < 4; ++i) {
      const int row = wr * 64 + i * 16 + fr_row;
      fah[i] = *(const bf16x8*)&sAh[buf][row * 32 + fr_swz];
    }
#pragma unroll
    for (int j = 0; j < 2; ++j) {
      const int row = wc * 32 + j * 16 + fr_row;
      fbh[j] = *(const bf16x8*)&sBh[buf][row * 32 + fr_swz];
      fbl[j] = *(const bf16x8*)&sBl[buf][row * 32 + fr_swz];
    }
#pragma unroll
    for (int i = 0; i < 4; ++i)
#pragma unroll
      for (int j = 0; j < 2; ++j) {
        acc[i][j] = __builtin_amdgcn_mfma_f32_16x16x32_bf16(fah[i], fbh[j], acc[i][j], 0, 0, 0);
        acc[i][j] = __builtin_amdgcn_mfma_f32_16x16x32_bf16(fah[i], fbl[j], acc[i][j], 0, 0, 0);
      }
    if (ks < 5) __syncthreads();
  }

  const int er = (lane >> 4) << 2;  // C/D: col=lane&15, row=(lane>>4)*4+reg
  const int ec = lane & 15;
#pragma unroll
  for (int i = 0; i < 4; ++i)
#pragma unroll
    for (int j = 0; j < 2; ++j) {
      float* cp = &Co[(size_t)(m0 + wr * 64 + i * 16 + er) * N + n0 + wc * 32 + j * 16 + ec];
#pragma unroll
      for (int r = 0; r < 4; ++r) cp[(size_t)r * N] = acc[i][j][r];
    }
}

// ---- depthwise 3x3 SAME, y-blocked x2 --------------------------------------
// q,k -> packed uint (hi | lo<<16) qkp[p][384]; v -> bf16 hi only [p][192]
__global__ __launch_bounds__(256) void dwconv3x3_v2(const float* __restrict__ in,
                                                    const float* __restrict__ wdw,
                                                    unsigned int* __restrict__ qkp,
                                                    unsigned short* __restrict__ vh) {
  const int t = blockIdx.x * 256 + threadIdx.x;
  const int c4 = t % 144;
  const int pix2 = t / 144;          // (img, y-pair, x)
  const int x = pix2 & 127;
  const int yp = (pix2 >> 7) & 63;
  const int img = pix2 >> 13;
  const int y0 = yp * 2;

  float4 wt[3][3];
#pragma unroll
  for (int i = 0; i < 3; ++i)
#pragma unroll
    for (int j = 0; j < 3; ++j)
      wt[i][j] = *(const float4*)&wdw[(size_t)(i * 3 + j) * C3 + c4 * 4];

  float4 tap[4][3];
  const bool interior = ((unsigned)(x - 1) < 126u) && ((unsigned)(yp - 1) < 62u);
  if (interior) {
    const float* base = &in[((size_t)(img << 14) + (y0 << 7) + x) * C3 + c4 * 4];
#pragma unroll
    for (int i = 0; i < 4; ++i)
#pragma unroll
      for (int j = 0; j < 3; ++j)
        tap[i][j] = *(const float4*)&base[(size_t)((i - 1) * 128 + (j - 1)) * C3];
  } else {
#pragma unroll
    for (int i = 0; i < 4; ++i) {
      const int ry = y0 - 1 + i;
      const int ryc = ry < 0 ? 0 : (ry > 127 ? 127 : ry);
      const bool vy = (unsigned)ry < 128u;
#pragma unroll
      for (int j = 0; j < 3; ++j) {
        const int rx = x - 1 + j;
        const int rxc = rx < 0 ? 0 : (rx > 127 ? 127 : rx);
        float4 v = *(const float4*)&in[((size_t)(img << 14) + (ryc << 7) + rxc) * C3 + c4 * 4];
        if (!(vy && ((unsigned)rx < 128u))) v = make_float4(0.f, 0.f, 0.f, 0.f);
        tap[i][j] = v;
      }
    }
  }

  float4 out0 = make_float4(0.f, 0.f, 0.f, 0.f);
  float4 out1 = make_float4(0.f, 0.f, 0.f, 0.f);
#pragma unroll
  for (int i = 0; i < 3; ++i)
#pragma unroll
    for (int j = 0; j < 3; ++j) {
      const float4 w = wt[i][j];
      const float4 a = tap[i][j];
      const float4 b = tap[i + 1][j];
      out0.x += a.x * w.x; out0.y += a.y * w.y; out0.z += a.z * w.z; out0.w += a.w * w.w;
      out1.x += b.x * w.x; out1.y += b.y * w.y; out1.z += b.z * w.z; out1.w += b.w * w.w;
    }

  const int p0 = (img << 14) + (y0 << 7) + x;
  const int p1 = p0 + 128;
  const float v0[4] = {out0.x, out0.y, out0.z, out0.w};
  const float v1[4] = {out1.x, out1.y, out1.z, out1.w};
  if (c4 < 96) {
    uint4 a, b;
    unsigned* ap = (unsigned*)&a;
    unsigned* bp = (unsigned*)&b;
#pragma unroll
    for (int j = 0; j < 4; ++j) {
      unsigned short h0 = f2bf(v0[j]);
      unsigned short l0 = f2bf(v0[j] - bf2f(h0));
      ap[j] = (unsigned)h0 | ((unsigned)l0 << 16);
      unsigned short h1 = f2bf(v1[j]);
      unsigned short l1 = f2bf(v1[j] - bf2f(h1));
      bp[j] = (unsigned)h1 | ((unsigned)l1 << 16);
    }
    *(uint4*)&qkp[(size_t)p0 * 384 + c4 * 4] = a;
    *(uint4*)&qkp[(size_t)p1 * 384 + c4 * 4] = b;
  } else {
    const int cc = (c4 - 96) * 4;
    ushort4 h0, h1;
    unsigned short *h0p = (unsigned short*)&h0, *h1p = (unsigned short*)&h1;
#pragma unroll
    for (int j = 0; j < 4; ++j) {
      h0p[j] = f2bf(v0[j]);
      h1p[j] = f2bf(v1[j]);
    }
    *(ushort4*)&vh[(size_t)p0 * 192 + cc] = h0;
    *(ushort4*)&vh[(size_t)p1 * 192 + cc] = h1;
  }
}

// ------- Gram v3 (MFMA): G = Q^T K per (img,h), 3-pass bf16; + ssq ----------
__global__ __launch_bounds__(256) void gram48_mfma(const unsigned int* __restrict__ qkp,
                                                   float* __restrict__ G,
                                                   float* __restrict__ ssqq,
                                                   float* __restrict__ ssqk) {
  constexpr int W = 50;
  __shared__ unsigned int smem[2 * 128 * W];   // sq | sk; reused as f32 reduce buf
  unsigned int* sq = smem;
  unsigned int* sk = smem + 128 * W;
  const int tid = threadIdx.x;
  const int lane = tid & 63;
  const int wv = tid >> 6;
  const int pair = blockIdx.y;          // img*4 + h  (img local to pass)
  const int img = pair >> 2, h = pair & 3;
  const int qcol = h * 48;
  const int kcol = 192 + h * 48;

  f32x4 acc[3][3] = {};
  float ssq_acc = 0.f;
  const int sch = tid % 96;
  const int shalf = tid / 96;

  for (int rnd = 0; rnd < 2; ++rnd) {
    const int sbase = (img << 14) + blockIdx.x * 256 + rnd * 128;
#pragma unroll
    for (int r = 0; r < 6; ++r) {
      const int idx = tid + (r << 8);    // 0..1535 = 128 rows x 12 uint4
      const int row = idx / 12, cc = (idx % 12) * 4;
      const uint4 vq = *(const uint4*)&qkp[(size_t)(sbase + row) * 384 + qcol + cc];
      const uint4 vk = *(const uint4*)&qkp[(size_t)(sbase + row) * 384 + kcol + cc];
      unsigned int* dq = &sq[row * W + cc];
      unsigned int* dk = &sk[row * W + cc];
      *(uint2*)dq = make_uint2(vq.x, vq.y);
      *(uint2*)(dq + 2) = make_uint2(vq.z, vq.w);
      *(uint2*)dk = make_uint2(vk.x, vk.y);
      *(uint2*)(dk + 2) = make_uint2(vk.z, vk.w);
    }
    __syncthreads();
    {
      const int s0 = wv * 32 + ((lane >> 4) << 3);
      const int cm = lane & 15;
      bf16x8 qh[3], ql[3], kh[3], kl[3];
#pragma unroll
      for (int t3 = 0; t3 < 3; ++t3) {
#pragma unroll
        for (int j = 0; j < 8; ++j) {
          const unsigned int uq = sq[(s0 + j) * W + t3 * 16 + cm];
          const unsigned int uk = sk[(s0 + j) * W + t3 * 16 + cm];
          qh[t3][j] = (short)(uq & 0xffffu);
          ql[t3][j] = (short)(uq >> 16);
          kh[t3][j] = (short)(uk & 0xffffu);
          kl[t3][j] = (short)(uk >> 16);
        }
      }
#pragma unroll
      for (int mt = 0; mt < 3; ++mt)
#pragma unroll
        for (int nt = 0; nt < 3; ++nt) {
          acc[mt][nt] = __builtin_amdgcn_mfma_f32_16x16x32_bf16(qh[mt], kh[nt], acc[mt][nt], 0, 0, 0);
          acc[mt][nt] = __builtin_amdgcn_mfma_f32_16x16x32_bf16(qh[mt], kl[nt], acc[mt][nt], 0, 0, 0);
          acc[mt][nt] = __builtin_amdgcn_mfma_f32_16x16x32_bf16(ql[mt], kh[nt], acc[mt][nt], 0, 0, 0);
        }
    }
    if (tid < 192) {
      const unsigned int* srcb = (sch < 48) ? &sq[sch] : &sk[sch - 48];
      const int sstart = shalf * 64;
#pragma unroll 4
      for (int s = 0; s < 64; ++s) {
        const unsigned int u = srcb[(size_t)(sstart + s) * W];
        const float v = bf2f((unsigned short)(u & 0xffffu)) + bf2f((unsigned short)(u >> 16));
        ssq_acc += v * v;
      }
    }
    __syncthreads();
  }

  float* red = (float*)smem;
  const int col = lane & 15;
  const int rbase = (lane >> 4) * 4;
#pragma unroll
  for (int mt = 0; mt < 3; ++mt)
#pragma unroll
    for (int nt = 0; nt < 3; ++nt)
#pragma unroll
      for (int rg = 0; rg < 4; ++rg)
        red[wv * 2304 + (mt * 16 + rbase + rg) * 48 + nt * 16 + col] = acc[mt][nt][rg];
  __syncthreads();
  float* Gm = &G[(size_t)pair * 2304];
#pragma unroll
  for (int c = 0; c < 9; ++c) {
    const int cell = tid + (c << 8);
    const float s4 = red[cell] + red[2304 + cell] + red[4608 + cell] + red[6912 + cell];
    atomicAdd(&Gm[cell], s4);
  }
  if (tid < 192) {
    if (sch < 48) atomicAdd(&ssqq[img * 192 + h * 48 + sch], ssq_acc);
    else          atomicAdd(&ssqk[img * 192 + h * 48 + sch - 48], ssq_acc);
  }
}

// ---- softmax over d of G*temp/(|q||k|), one wave per (img,h,row) -----------
__global__ __launch_bounds__(64) void attn_softmax(const float* __restrict__ G,
                                                   const float* __restrict__ ssqq,
                                                   const float* __restrict__ ssqk,
                                                   const float* __restrict__ temp,
                                                   float* __restrict__ attn) {
  const int r = blockIdx.x;          // 0..47
  const int h = blockIdx.y & 3;
  const int img = blockIdx.y >> 2;
  const int lane = threadIdx.x;
  const size_t base = (size_t)(img * 4 + h) * 2304;
  const float t = temp[h];
  const float qn = ssqq[img * 192 + h * CH + r];
  float val = -1e30f;
  if (lane < 48) {
    const float kn = ssqk[img * 192 + h * CH + lane];
    val = G[base + r * 48 + lane] * t * rsqrtf(qn * kn);
  }
  float m = val;
#pragma unroll
  for (int off = 32; off; off >>= 1) m = fmaxf(m, __shfl_xor(m, off));
  const float e = (lane < 48) ? expf(val - m) : 0.f;
  float ssum = e;
#pragma unroll
  for (int off = 32; off; off >>= 1) ssum += __shfl_xor(ssum, off);
  if (lane < 48) attn[base + r * 48 + lane] = e / ssum;
}

// ---- W_eff^T[img][n][D] = sum_c' A[img][h(D)][c'][D%48] * Wp[48h+c'][n] ----
__global__ __launch_bounds__(256) void make_weff(const float* __restrict__ attn,
                                                 const float* __restrict__ wproj,
                                                 unsigned short* __restrict__ weh,
                                                 unsigned short* __restrict__ wel) {
  const int t = blockIdx.x * 256 + threadIdx.x;   // over NI*192*192
  const int img = t / 36864;
  const int r = t % 36864;
  const int n = r / 192;
  const int D = r % 192;
  const int h = D / 48, dd = D % 48;
  const float* A = &attn[(size_t)(img * 4 + h) * 2304 + dd];
  const float* Wp = &wproj[(size_t)(h * 48) * 192 + n];
  float acc = 0.f;
#pragma unroll
  for (int c = 0; c < 48; ++c) acc += A[c * 48] * Wp[c * 192];
  const unsigned short hb = f2bf(acc);
  weh[(size_t)img * 36864 + n * 192 + D] = hb;
  wel[(size_t)img * 36864 + n * 192 + D] = f2bf(acc - bf2f(hb));
}

}  // namespace

extern "C" void kernel_launch(void* const* d_in, const int* in_sizes, int n_in,
                              void* d_out, int out_size, void* d_ws, size_t ws_size,
                              hipStream_t stream) {
  const float* x      = (const float*)d_in[0];
  const float* w_qkv  = (const float*)d_in[1];
  const float* w_dw   = (const float*)d_in[2];
  const float* w_proj = (const float*)d_in[3];
  const float* temp   = (const float*)d_in[4];
  float* out = (float*)d_out;

  // NI images per pass. NI=2 ≈ 166 MB (ws is 256 MiB), NI=1 ≈ 103 MB.
  auto layout_bytes = [](int NI) -> size_t {
    return (size_t)NI * HW * 576 * 4       // qkv fp32
         + (size_t)NI * HW * 384 * 4       // qkp packed uint (q,k hi|lo)
         + (size_t)NI * HW * 192 * 2       // vh (bf16 only)
         + (size_t)4 * HW * 192 * 2        // xh (all 4 images)
         + 2 * 221184                      // wqh, wql
         + 153600                          // G, ssqq, ssqk (all 4 images)
         + 147456                          // attnb (all 4 images)
         + 2 * 294912;                     // weh, wel (all 4 images)
  };
  const int NI = (ws_size >= layout_bytes(2)) ? 2 : 1;
  const int npass = 4 / NI;
  const int npix = NI * HW;

  char* p = (char*)d_ws;
  float* qkv = (float*)p;            p += (size_t)npix * 576 * 4;
  unsigned int* qkp = (unsigned int*)p;     p += (size_t)npix * 384 * 4;
  unsigned short* vh = (unsigned short*)p;  p += (size_t)npix * 192 * 2;
  unsigned short* xh = (unsigned short*)p;  p += (size_t)4 * HW * 192 * 2;
  unsigned short* wqh = (unsigned short*)p; p += 221184;
  unsigned short* wql = (unsigned short*)p; p += 221184;
  float* G    = (float*)p;           p += 147456;   // 16 (img,h) pairs
  float* ssqq = (float*)p;           p += 3072;     // 4 img x 192
  float* ssqk = (float*)p;           p += 3072;
  float* attnb = (float*)p;          p += 147456;
  unsigned short* weh = (unsigned short*)p; p += 294912;
  unsigned short* wel = (unsigned short*)p;

  cvt_wqkv<<<432, 256, 0, stream>>>(w_qkv, wqh, wql);
  cvt_x<<<4 * HW * 192 / 1024, 256, 0, stream>>>(x, xh);
  hipMemsetAsync(G, 0, 153600, stream);  // G+ssqq+ssqk, all 4 images, once

  for (int pass = 0; pass < npass; ++pass) {
    const size_t arow = (size_t)pass * npix * 192;
    float* outb = out + (size_t)pass * npix * C;
    float* Gp    = G + (size_t)pass * NI * 4 * 2304;
    float* sqp   = ssqq + (size_t)pass * NI * 192;
    float* skp   = ssqk + (size_t)pass * NI * 192;
    float* ap    = attnb + (size_t)pass * NI * 4 * 2304;
    unsigned short* wehp = weh + (size_t)pass * NI * 36864;
    unsigned short* welp = wel + (size_t)pass * NI * 36864;
    gemm_mfma<576, false><<<dim3(npix / 128, 9), 256, 0, stream>>>(
        xh + arow, wqh, wql, qkv);
    dwconv3x3_v2<<<npix * 72 / 256, 256, 0, stream>>>(qkv, w_dw, qkp, vh);
    gram48_mfma<<<dim3(64, 4 * NI), 256, 0, stream>>>(qkp, Gp, sqp, skp);
    attn_softmax<<<dim3(48, 4 * NI), 64, 0, stream>>>(Gp, sqp, skp, temp, ap);
    make_weff<<<NI * 144, 256, 0, stream>>>(ap, w_proj, wehp, welp);
    gemm_mfma<192, true><<<dim3(npix / 128, 3), 256, 0, stream>>>(
        vh, wehp, welp, outb);
  }
}

// Round 10
// 185.886 us; speedup vs baseline: 1.3473x; 1.0987x over previous
//
#include <hip/hip_runtime.h>

namespace {

constexpr int HW = 16384;   // pixels per image
constexpr int C  = 192;
constexpr int C3 = 576;
constexpr int CH = 48;
constexpr int K  = 192;

using bf16x8 = __attribute__((ext_vector_type(8))) short;
using f32x4  = __attribute__((ext_vector_type(4))) float;

__device__ inline unsigned short f2bf(float f) {
  unsigned u = __float_as_uint(f);
  unsigned r = (u + 0x7fff + ((u >> 16) & 1)) >> 16;
  return (unsigned short)r;
}
__device__ inline float bf2f(unsigned short b) {
  return __uint_as_float(((unsigned)b) << 16);
}
__device__ inline float4 ld_bf4(const unsigned short* p) {
  const ushort4 u = *(const ushort4*)p;
  return make_float4(bf2f(u.x), bf2f(u.y), bf2f(u.z), bf2f(u.w));
}

// async global->LDS, 16B per lane. LDS dest = wave-uniform base + lane*16.
__device__ __forceinline__ void ld_g2l16(const unsigned short* g, unsigned short* l) {
  __builtin_amdgcn_global_load_lds(
      (const __attribute__((address_space(1))) unsigned int*)(unsigned long long)(const void*)g,
      (__attribute__((address_space(3))) unsigned int*)(unsigned int)(unsigned long long)(void*)l,
      16, 0, 0);
}

// ---- fp32 -> bf16 (hi only; 2-pass Markidis keeps lo only on the B side) ---
__global__ __launch_bounds__(256) void cvt_x(const float* __restrict__ in,
                                             unsigned short* __restrict__ hi) {
  const int t = blockIdx.x * 256 + threadIdx.x;
  const float4 v = ((const float4*)in)[t];
  ((ushort4*)hi)[t] = make_ushort4(f2bf(v.x), f2bf(v.y), f2bf(v.z), f2bf(v.w));
}

// ---- transpose + split qkv weights: [192,576] -> hi/lo [576][192] ----------
__global__ __launch_bounds__(256) void cvt_wqkv(const float* __restrict__ wqkv,
                                                unsigned short* __restrict__ wqh,
                                                unsigned short* __restrict__ wql) {
  const int t = blockIdx.x * 256 + threadIdx.x;  // 0 .. 576*192-1
  const int n = t / 192;
  const int k = t % 192;
  const float v = wqkv[k * C3 + n];
  const unsigned short h = f2bf(v);
  wqh[n * 192 + k] = h;
  wql[n * 192 + k] = f2bf(v - bf2f(h));
}

// ---- MFMA GEMM: Co[M,N] = Ah[M,192] @ (Bh+Bl)[N,192]^T, 2-pass bf16 --------
// OBF16: emit bf16 output (qkv path); else fp32 (final out).
template <int N, bool PERB, bool OBF16>
__global__ __launch_bounds__(256, 4) void gemm_mfma(const unsigned short* __restrict__ Ah,
                                                    const unsigned short* __restrict__ Bh,
                                                    const unsigned short* __restrict__ Bl,
                                                    void* __restrict__ Co) {
  __shared__ __align__(16) unsigned short sAh[2][128 * 32];
  __shared__ __align__(16) unsigned short sBh[2][64 * 32];
  __shared__ __align__(16) unsigned short sBl[2][64 * 32];
  const int t = threadIdx.x;
  const int lane = t & 63;
  const int wv = t >> 6;
  const int m0 = blockIdx.x * 128;
  const int n0 = blockIdx.y * 64;
  const size_t boff = PERB ? (size_t)(m0 >> 14) * (192 * 192) : 0;
  const int wr = wv >> 1, wc = wv & 1;
  const int fr_row = lane & 15;
  const int fr_swz = ((lane >> 4) ^ (lane & 3)) << 3;

  // staging geometry: LDS[row][phys_slot] = global[row][phys_slot ^ (row&3)]
  const int arow0 = wv * 32;           // A rows per wave: 2 issues of 16 rows
  const int lrow  = lane >> 2;
  const int lslot = lane & 3;
  const int brow0 = wv * 16;           // B rows per wave: 1 issue

  f32x4 acc[4][2] = {};

  auto stage = [&](int buf, int k0) {
#pragma unroll
    for (int r = 0; r < 2; ++r) {
      const int row = arow0 + r * 16 + lrow;
      const int ssl = lslot ^ (row & 3);
      const size_t go = (size_t)(m0 + row) * K + k0 + (ssl << 3);
      ld_g2l16(&Ah[go], &sAh[buf][(arow0 + r * 16) * 32]);
    }
    {
      const int row = brow0 + lrow;
      const int ssl = lslot ^ (row & 3);
      const size_t go = boff + (size_t)(n0 + row) * K + k0 + (ssl << 3);
      ld_g2l16(&Bh[go], &sBh[buf][brow0 * 32]);
      ld_g2l16(&Bl[go], &sBl[buf][brow0 * 32]);
    }
  };

  stage(0, 0);
  __syncthreads();
#pragma unroll
  for (int ks = 0; ks < 6; ++ks) {
    if (ks < 5) stage((ks + 1) & 1, (ks + 1) * 32);
    const int buf = ks & 1;
    bf16x8 fah[4], fbh[2], fbl[2];
#pragma unroll
    for (int i = 0; i < 4; ++i) {
      const int row = wr * 64 + i * 16 + fr_row;
      fah[i] = *(const bf16x8*)&sAh[buf][row * 32 + fr_swz];
    }
#pragma unroll
    for (int j = 0; j < 2; ++j) {
      const int row = wc * 32 + j * 16 + fr_row;
      fbh[j] = *(const bf16x8*)&sBh[buf][row * 32 + fr_swz];
      fbl[j] = *(const bf16x8*)&sBl[buf][row * 32 + fr_swz];
    }
#pragma unroll
    for (int i = 0; i < 4; ++i)
#pragma unroll
      for (int j = 0; j < 2; ++j) {
        acc[i][j] = __builtin_amdgcn_mfma_f32_16x16x32_bf16(fah[i], fbh[j], acc[i][j], 0, 0, 0);
        acc[i][j] = __builtin_amdgcn_mfma_f32_16x16x32_bf16(fah[i], fbl[j], acc[i][j], 0, 0, 0);
      }
    if (ks < 5) __syncthreads();
  }

  const int er = (lane >> 4) << 2;  // C/D: col=lane&15, row=(lane>>4)*4+reg
  const int ec = lane & 15;
#pragma unroll
  for (int i = 0; i < 4; ++i)
#pragma unroll
    for (int j = 0; j < 2; ++j) {
      const size_t base = (size_t)(m0 + wr * 64 + i * 16 + er) * N + n0 + wc * 32 + j * 16 + ec;
      if constexpr (OBF16) {
        unsigned short* cp = (unsigned short*)Co + base;
#pragma unroll
        for (int r = 0; r < 4; ++r) cp[(size_t)r * N] = f2bf(acc[i][j][r]);
      } else {
        float* cp = (float*)Co + base;
#pragma unroll
        for (int r = 0; r < 4; ++r) cp[(size_t)r * N] = acc[i][j][r];
      }
    }
}

// ---- depthwise 3x3 SAME, y-blocked x2, bf16 input --------------------------
// q,k -> packed uint (hi | lo<<16) qkp[p][384]; v -> bf16 [p][192]
__global__ __launch_bounds__(256) void dwconv3x3_v3(const unsigned short* __restrict__ in,
                                                    const float* __restrict__ wdw,
                                                    unsigned int* __restrict__ qkp,
                                                    unsigned short* __restrict__ vh) {
  const int t = blockIdx.x * 256 + threadIdx.x;
  const int c4 = t % 144;
  const int pix2 = t / 144;          // (img, y-pair, x)
  const int x = pix2 & 127;
  const int yp = (pix2 >> 7) & 63;
  const int img = pix2 >> 13;
  const int y0 = yp * 2;

  float4 wt[3][3];
#pragma unroll
  for (int i = 0; i < 3; ++i)
#pragma unroll
    for (int j = 0; j < 3; ++j)
      wt[i][j] = *(const float4*)&wdw[(size_t)(i * 3 + j) * C3 + c4 * 4];

  float4 tap[4][3];
  const bool interior = ((unsigned)(x - 1) < 126u) && ((unsigned)(yp - 1) < 62u);
  if (interior) {
    const unsigned short* base = &in[((size_t)(img << 14) + (y0 << 7) + x) * C3 + c4 * 4];
#pragma unroll
    for (int i = 0; i < 4; ++i)
#pragma unroll
      for (int j = 0; j < 3; ++j)
        tap[i][j] = ld_bf4(&base[(ptrdiff_t)((i - 1) * 128 + (j - 1)) * C3]);
  } else {
#pragma unroll
    for (int i = 0; i < 4; ++i) {
      const int ry = y0 - 1 + i;
      const int ryc = ry < 0 ? 0 : (ry > 127 ? 127 : ry);
      const bool vy = (unsigned)ry < 128u;
#pragma unroll
      for (int j = 0; j < 3; ++j) {
        const int rx = x - 1 + j;
        const int rxc = rx < 0 ? 0 : (rx > 127 ? 127 : rx);
        float4 v = ld_bf4(&in[((size_t)(img << 14) + (ryc << 7) + rxc) * C3 + c4 * 4]);
        if (!(vy && ((unsigned)rx < 128u))) v = make_float4(0.f, 0.f, 0.f, 0.f);
        tap[i][j] = v;
      }
    }
  }

  float4 out0 = make_float4(0.f, 0.f, 0.f, 0.f);
  float4 out1 = make_float4(0.f, 0.f, 0.f, 0.f);
#pragma unroll
  for (int i = 0; i < 3; ++i)
#pragma unroll
    for (int j = 0; j < 3; ++j) {
      const float4 w = wt[i][j];
      const float4 a = tap[i][j];
      const float4 b = tap[i + 1][j];
      out0.x += a.x * w.x; out0.y += a.y * w.y; out0.z += a.z * w.z; out0.w += a.w * w.w;
      out1.x += b.x * w.x; out1.y += b.y * w.y; out1.z += b.z * w.z; out1.w += b.w * w.w;
    }

  const int p0 = (img << 14) + (y0 << 7) + x;
  const int p1 = p0 + 128;
  const float v0[4] = {out0.x, out0.y, out0.z, out0.w};
  const float v1[4] = {out1.x, out1.y, out1.z, out1.w};
  if (c4 < 96) {
    uint4 a, b;
    unsigned* ap = (unsigned*)&a;
    unsigned* bp = (unsigned*)&b;
#pragma unroll
    for (int j = 0; j < 4; ++j) {
      unsigned short h0 = f2bf(v0[j]);
      unsigned short l0 = f2bf(v0[j] - bf2f(h0));
      ap[j] = (unsigned)h0 | ((unsigned)l0 << 16);
      unsigned short h1 = f2bf(v1[j]);
      unsigned short l1 = f2bf(v1[j] - bf2f(h1));
      bp[j] = (unsigned)h1 | ((unsigned)l1 << 16);
    }
    *(uint4*)&qkp[(size_t)p0 * 384 + c4 * 4] = a;
    *(uint4*)&qkp[(size_t)p1 * 384 + c4 * 4] = b;
  } else {
    const int cc = (c4 - 96) * 4;
    ushort4 h0, h1;
    unsigned short *h0p = (unsigned short*)&h0, *h1p = (unsigned short*)&h1;
#pragma unroll
    for (int j = 0; j < 4; ++j) {
      h0p[j] = f2bf(v0[j]);
      h1p[j] = f2bf(v1[j]);
    }
    *(ushort4*)&vh[(size_t)p0 * 192 + cc] = h0;
    *(ushort4*)&vh[(size_t)p1 * 192 + cc] = h1;
  }
}

// ------- Gram v3 (MFMA): G = Q^T K per (img,h), 3-pass bf16; + ssq ----------
__global__ __launch_bounds__(256) void gram48_mfma(const unsigned int* __restrict__ qkp,
                                                   float* __restrict__ G,
                                                   float* __restrict__ ssqq,
                                                   float* __restrict__ ssqk) {
  constexpr int W = 50;
  __shared__ unsigned int smem[2 * 128 * W];   // sq | sk; reused as f32 reduce buf
  unsigned int* sq = smem;
  unsigned int* sk = smem + 128 * W;
  const int tid = threadIdx.x;
  const int lane = tid & 63;
  const int wv = tid >> 6;
  const int pair = blockIdx.y;          // img*4 + h
  const int img = pair >> 2, h = pair & 3;
  const int qcol = h * 48;
  const int kcol = 192 + h * 48;

  f32x4 acc[3][3] = {};
  float ssq_acc = 0.f;
  const int sch = tid % 96;
  const int shalf = tid / 96;

  for (int rnd = 0; rnd < 2; ++rnd) {
    const int sbase = (img << 14) + blockIdx.x * 256 + rnd * 128;
#pragma unroll
    for (int r = 0; r < 6; ++r) {
      const int idx = tid + (r << 8);    // 0..1535 = 128 rows x 12 uint4
      const int row = idx / 12, cc = (idx % 12) * 4;
      const uint4 vq = *(const uint4*)&qkp[(size_t)(sbase + row) * 384 + qcol + cc];
      const uint4 vk = *(const uint4*)&qkp[(size_t)(sbase + row) * 384 + kcol + cc];
      unsigned int* dq = &sq[row * W + cc];
      unsigned int* dk = &sk[row * W + cc];
      *(uint2*)dq = make_uint2(vq.x, vq.y);
      *(uint2*)(dq + 2) = make_uint2(vq.z, vq.w);
      *(uint2*)dk = make_uint2(vk.x, vk.y);
      *(uint2*)(dk + 2) = make_uint2(vk.z, vk.w);
    }
    __syncthreads();
    {
      const int s0 = wv * 32 + ((lane >> 4) << 3);
      const int cm = lane & 15;
      bf16x8 qh[3], ql[3], kh[3], kl[3];
#pragma unroll
      for (int t3 = 0; t3 < 3; ++t3) {
#pragma unroll
        for (int j = 0; j < 8; ++j) {
          const unsigned int uq = sq[(s0 + j) * W + t3 * 16 + cm];
          const unsigned int uk = sk[(s0 + j) * W + t3 * 16 + cm];
          qh[t3][j] = (short)(uq & 0xffffu);
          ql[t3][j] = (short)(uq >> 16);
          kh[t3][j] = (short)(uk & 0xffffu);
          kl[t3][j] = (short)(uk >> 16);
        }
      }
#pragma unroll
      for (int mt = 0; mt < 3; ++mt)
#pragma unroll
        for (int nt = 0; nt < 3; ++nt) {
          acc[mt][nt] = __builtin_amdgcn_mfma_f32_16x16x32_bf16(qh[mt], kh[nt], acc[mt][nt], 0, 0, 0);
          acc[mt][nt] = __builtin_amdgcn_mfma_f32_16x16x32_bf16(qh[mt], kl[nt], acc[mt][nt], 0, 0, 0);
          acc[mt][nt] = __builtin_amdgcn_mfma_f32_16x16x32_bf16(ql[mt], kh[nt], acc[mt][nt], 0, 0, 0);
        }
    }
    if (tid < 192) {
      const unsigned int* srcb = (sch < 48) ? &sq[sch] : &sk[sch - 48];
      const int sstart = shalf * 64;
#pragma unroll 4
      for (int s = 0; s < 64; ++s) {
        const unsigned int u = srcb[(size_t)(sstart + s) * W];
        const float v = bf2f((unsigned short)(u & 0xffffu)) + bf2f((unsigned short)(u >> 16));
        ssq_acc += v * v;
      }
    }
    __syncthreads();
  }

  float* red = (float*)smem;
  const int col = lane & 15;
  const int rbase = (lane >> 4) * 4;
#pragma unroll
  for (int mt = 0; mt < 3; ++mt)
#pragma unroll
    for (int nt = 0; nt < 3; ++nt)
#pragma unroll
      for (int rg = 0; rg < 4; ++rg)
        red[wv * 2304 + (mt * 16 + rbase + rg) * 48 + nt * 16 + col] = acc[mt][nt][rg];
  __syncthreads();
  float* Gm = &G[(size_t)pair * 2304];
#pragma unroll
  for (int c = 0; c < 9; ++c) {
    const int cell = tid + (c << 8);
    const float s4 = red[cell] + red[2304 + cell] + red[4608 + cell] + red[6912 + cell];
    atomicAdd(&Gm[cell], s4);
  }
  if (tid < 192) {
    if (sch < 48) atomicAdd(&ssqq[img * 192 + h * 48 + sch], ssq_acc);
    else          atomicAdd(&ssqk[img * 192 + h * 48 + sch - 48], ssq_acc);
  }
}

// ---- softmax over d of G*temp/(|q||k|), one wave per (img,h,row) -----------
__global__ __launch_bounds__(64) void attn_softmax(const float* __restrict__ G,
                                                   const float* __restrict__ ssqq,
                                                   const float* __restrict__ ssqk,
                                                   const float* __restrict__ temp,
                                                   float* __restrict__ attn) {
  const int r = blockIdx.x;          // 0..47
  const int h = blockIdx.y & 3;
  const int img = blockIdx.y >> 2;
  const int lane = threadIdx.x;
  const size_t base = (size_t)(img * 4 + h) * 2304;
  const float t = temp[h];
  const float qn = ssqq[img * 192 + h * CH + r];
  float val = -1e30f;
  if (lane < 48) {
    const float kn = ssqk[img * 192 + h * CH + lane];
    val = G[base + r * 48 + lane] * t * rsqrtf(qn * kn);
  }
  float m = val;
#pragma unroll
  for (int off = 32; off; off >>= 1) m = fmaxf(m, __shfl_xor(m, off));
  const float e = (lane < 48) ? expf(val - m) : 0.f;
  float ssum = e;
#pragma unroll
  for (int off = 32; off; off >>= 1) ssum += __shfl_xor(ssum, off);
  if (lane < 48) attn[base + r * 48 + lane] = e / ssum;
}

// ---- W_eff^T[img][n][D] = sum_c' A[img][h(D)][c'][D%48] * Wp[48h+c'][n] ----
__global__ __launch_bounds__(256) void make_weff(const float* __restrict__ attn,
                                                 const float* __restrict__ wproj,
                                                 unsigned short* __restrict__ weh,
                                                 unsigned short* __restrict__ wel) {
  const int t = blockIdx.x * 256 + threadIdx.x;   // over NI*192*192
  const int img = t / 36864;
  const int r = t % 36864;
  const int n = r / 192;
  const int D = r % 192;
  const int h = D / 48, dd = D % 48;
  const float* A = &attn[(size_t)(img * 4 + h) * 2304 + dd];
  const float* Wp = &wproj[(size_t)(h * 48) * 192 + n];
  float acc = 0.f;
#pragma unroll
  for (int c = 0; c < 48; ++c) acc += A[c * 48] * Wp[c * 192];
  const unsigned short hb = f2bf(acc);
  weh[(size_t)img * 36864 + n * 192 + D] = hb;
  wel[(size_t)img * 36864 + n * 192 + D] = f2bf(acc - bf2f(hb));
}

}  // namespace

extern "C" void kernel_launch(void* const* d_in, const int* in_sizes, int n_in,
                              void* d_out, int out_size, void* d_ws, size_t ws_size,
                              hipStream_t stream) {
  const float* x      = (const float*)d_in[0];
  const float* w_qkv  = (const float*)d_in[1];
  const float* w_dw   = (const float*)d_in[2];
  const float* w_proj = (const float*)d_in[3];
  const float* temp   = (const float*)d_in[4];
  float* out = (float*)d_out;

  // NI images per pass. NI=4 ≈ 217 MiB (bf16 qkv), fits the 256 MiB ws.
  auto layout_bytes = [](int NI) -> size_t {
    return (size_t)NI * HW * 576 * 2       // qkv bf16
         + (size_t)NI * HW * 384 * 4       // qkp packed uint (q,k hi|lo)
         + (size_t)NI * HW * 192 * 2       // vh (bf16)
         + (size_t)4 * HW * 192 * 2        // xh (all 4 images)
         + 2 * 221184                      // wqh, wql
         + 153600                          // G, ssqq, ssqk (all 4 images)
         + 147456                          // attnb (all 4 images)
         + 2 * 294912;                     // weh, wel (all 4 images)
  };
  const int NI = (ws_size >= layout_bytes(4)) ? 4 : ((ws_size >= layout_bytes(2)) ? 2 : 1);
  const int npass = 4 / NI;
  const int npix = NI * HW;

  char* p = (char*)d_ws;
  unsigned short* qkv = (unsigned short*)p; p += (size_t)npix * 576 * 2;
  unsigned int* qkp = (unsigned int*)p;     p += (size_t)npix * 384 * 4;
  unsigned short* vh = (unsigned short*)p;  p += (size_t)npix * 192 * 2;
  unsigned short* xh = (unsigned short*)p;  p += (size_t)4 * HW * 192 * 2;
  unsigned short* wqh = (unsigned short*)p; p += 221184;
  unsigned short* wql = (unsigned short*)p; p += 221184;
  float* G    = (float*)p;           p += 147456;   // 16 (img,h) pairs
  float* ssqq = (float*)p;           p += 3072;     // 4 img x 192
  float* ssqk = (float*)p;           p += 3072;
  float* attnb = (float*)p;          p += 147456;
  unsigned short* weh = (unsigned short*)p; p += 294912;
  unsigned short* wel = (unsigned short*)p;

  cvt_wqkv<<<432, 256, 0, stream>>>(w_qkv, wqh, wql);
  cvt_x<<<4 * HW * 192 / 1024, 256, 0, stream>>>(x, xh);
  hipMemsetAsync(G, 0, 153600, stream);  // G+ssqq+ssqk, all 4 images, once

  for (int pass = 0; pass < npass; ++pass) {
    const size_t arow = (size_t)pass * npix * 192;
    float* outb = out + (size_t)pass * npix * C;
    float* Gp    = G + (size_t)pass * NI * 4 * 2304;
    float* sqp   = ssqq + (size_t)pass * NI * 192;
    float* skp   = ssqk + (size_t)pass * NI * 192;
    float* ap    = attnb + (size_t)pass * NI * 4 * 2304;
    unsigned short* wehp = weh + (size_t)pass * NI * 36864;
    unsigned short* welp = wel + (size_t)pass * NI * 36864;
    gemm_mfma<576, false, true><<<dim3(npix / 128, 9), 256, 0, stream>>>(
        xh + arow, wqh, wql, qkv);
    dwconv3x3_v3<<<npix * 72 / 256, 256, 0, stream>>>(qkv, w_dw, qkp, vh);
    gram48_mfma<<<dim3(64, 4 * NI), 256, 0, stream>>>(qkp, Gp, sqp, skp);
    attn_softmax<<<dim3(48, 4 * NI), 64, 0, stream>>>(Gp, sqp, skp, temp, ap);
    make_weff<<<NI * 144, 256, 0, stream>>>(ap, w_proj, wehp, welp);
    gemm_mfma<192, true, false><<<dim3(npix / 128, 3), 256, 0, stream>>>(
        vh, wehp, welp, outb);
  }
}

// Round 11
// 175.604 us; speedup vs baseline: 1.4261x; 1.0585x over previous
//
#include <hip/hip_runtime.h>

namespace {

constexpr int HW = 16384;   // pixels per image
constexpr int C  = 192;
constexpr int C3 = 576;
constexpr int CH = 48;
constexpr int K  = 192;

using bf16x8 = __attribute__((ext_vector_type(8))) short;
using f32x4  = __attribute__((ext_vector_type(4))) float;

__device__ inline unsigned short f2bf(float f) {
  unsigned u = __float_as_uint(f);
  unsigned r = (u + 0x7fff + ((u >> 16) & 1)) >> 16;
  return (unsigned short)r;
}
__device__ inline float bf2f(unsigned short b) {
  return __uint_as_float(((unsigned)b) << 16);
}
__device__ inline float4 ld_bf4(const unsigned short* p) {
  const ushort4 u = *(const ushort4*)p;
  return make_float4(bf2f(u.x), bf2f(u.y), bf2f(u.z), bf2f(u.w));
}

// async global->LDS, 16B per lane. LDS dest = wave-uniform base + lane*16.
__device__ __forceinline__ void ld_g2l16(const unsigned short* g, unsigned short* l) {
  __builtin_amdgcn_global_load_lds(
      (const __attribute__((address_space(1))) unsigned int*)(unsigned long long)(const void*)g,
      (__attribute__((address_space(3))) unsigned int*)(unsigned int)(unsigned long long)(void*)l,
      16, 0, 0);
}

// ---- fp32 -> bf16 (hi only) ------------------------------------------------
__global__ __launch_bounds__(256) void cvt_x(const float* __restrict__ in,
                                             unsigned short* __restrict__ hi) {
  const int t = blockIdx.x * 256 + threadIdx.x;
  const float4 v = ((const float4*)in)[t];
  ((ushort4*)hi)[t] = make_ushort4(f2bf(v.x), f2bf(v.y), f2bf(v.z), f2bf(v.w));
}

// ---- transpose + split qkv weights: [192,576] -> hi/lo [576][192] ----------
__global__ __launch_bounds__(256) void cvt_wqkv(const float* __restrict__ wqkv,
                                                unsigned short* __restrict__ wqh,
                                                unsigned short* __restrict__ wql) {
  const int t = blockIdx.x * 256 + threadIdx.x;  // 0 .. 576*192-1
  const int n = t / 192;
  const int k = t % 192;
  const float v = wqkv[k * C3 + n];
  const unsigned short h = f2bf(v);
  wqh[n * 192 + k] = h;
  wql[n * 192 + k] = f2bf(v - bf2f(h));
}

// ---- MFMA GEMM: Co[M,N] = Ah[M,192] @ (Bh+Bl)[N,192]^T, 2-pass bf16 --------
// OBF16: emit bf16 output (qkv path); else fp32 (final out).
template <int N, bool PERB, bool OBF16>
__global__ __launch_bounds__(256, 4) void gemm_mfma(const unsigned short* __restrict__ Ah,
                                                    const unsigned short* __restrict__ Bh,
                                                    const unsigned short* __restrict__ Bl,
                                                    void* __restrict__ Co) {
  __shared__ __align__(16) unsigned short sAh[2][128 * 32];
  __shared__ __align__(16) unsigned short sBh[2][64 * 32];
  __shared__ __align__(16) unsigned short sBl[2][64 * 32];
  const int t = threadIdx.x;
  const int lane = t & 63;
  const int wv = t >> 6;
  const int m0 = blockIdx.x * 128;
  const int n0 = blockIdx.y * 64;
  const size_t boff = PERB ? (size_t)(m0 >> 14) * (192 * 192) : 0;
  const int wr = wv >> 1, wc = wv & 1;
  const int fr_row = lane & 15;
  const int fr_swz = ((lane >> 4) ^ (lane & 3)) << 3;

  // staging geometry: LDS[row][phys_slot] = global[row][phys_slot ^ (row&3)]
  const int arow0 = wv * 32;           // A rows per wave: 2 issues of 16 rows
  const int lrow  = lane >> 2;
  const int lslot = lane & 3;
  const int brow0 = wv * 16;           // B rows per wave: 1 issue

  f32x4 acc[4][2] = {};

  auto stage = [&](int buf, int k0) {
#pragma unroll
    for (int r = 0; r < 2; ++r) {
      const int row = arow0 + r * 16 + lrow;
      const int ssl = lslot ^ (row & 3);
      const size_t go = (size_t)(m0 + row) * K + k0 + (ssl << 3);
      ld_g2l16(&Ah[go], &sAh[buf][(arow0 + r * 16) * 32]);
    }
    {
      const int row = brow0 + lrow;
      const int ssl = lslot ^ (row & 3);
      const size_t go = boff + (size_t)(n0 + row) * K + k0 + (ssl << 3);
      ld_g2l16(&Bh[go], &sBh[buf][brow0 * 32]);
      ld_g2l16(&Bl[go], &sBl[buf][brow0 * 32]);
    }
  };

  stage(0, 0);
  __syncthreads();
#pragma unroll
  for (int ks = 0; ks < 6; ++ks) {
    if (ks < 5) stage((ks + 1) & 1, (ks + 1) * 32);
    const int buf = ks & 1;
    bf16x8 fah[4], fbh[2], fbl[2];
#pragma unroll
    for (int i = 0; i < 4; ++i) {
      const int row = wr * 64 + i * 16 + fr_row;
      fah[i] = *(const bf16x8*)&sAh[buf][row * 32 + fr_swz];
    }
#pragma unroll
    for (int j = 0; j < 2; ++j) {
      const int row = wc * 32 + j * 16 + fr_row;
      fbh[j] = *(const bf16x8*)&sBh[buf][row * 32 + fr_swz];
      fbl[j] = *(const bf16x8*)&sBl[buf][row * 32 + fr_swz];
    }
#pragma unroll
    for (int i = 0; i < 4; ++i)
#pragma unroll
      for (int j = 0; j < 2; ++j) {
        acc[i][j] = __builtin_amdgcn_mfma_f32_16x16x32_bf16(fah[i], fbh[j], acc[i][j], 0, 0, 0);
        acc[i][j] = __builtin_amdgcn_mfma_f32_16x16x32_bf16(fah[i], fbl[j], acc[i][j], 0, 0, 0);
      }
    if (ks < 5) __syncthreads();
  }

  const int er = (lane >> 4) << 2;  // C/D: col=lane&15, row=(lane>>4)*4+reg
  const int ec = lane & 15;
#pragma unroll
  for (int i = 0; i < 4; ++i)
#pragma unroll
    for (int j = 0; j < 2; ++j) {
      const size_t base = (size_t)(m0 + wr * 64 + i * 16 + er) * N + n0 + wc * 32 + j * 16 + ec;
      if constexpr (OBF16) {
        unsigned short* cp = (unsigned short*)Co + base;
#pragma unroll
        for (int r = 0; r < 4; ++r) cp[(size_t)r * N] = f2bf(acc[i][j][r]);
      } else {
        float* cp = (float*)Co + base;
#pragma unroll
        for (int r = 0; r < 4; ++r) cp[(size_t)r * N] = acc[i][j][r];
      }
    }
}

// ---- depthwise 3x3 SAME, y-blocked x2, bf16 in/out -------------------------
// q,k -> bf16 qk[p][384]; v -> bf16 vh[p][192]
__global__ __launch_bounds__(256) void dwconv3x3_v4(const unsigned short* __restrict__ in,
                                                    const float* __restrict__ wdw,
                                                    unsigned short* __restrict__ qk,
                                                    unsigned short* __restrict__ vh) {
  const int t = blockIdx.x * 256 + threadIdx.x;
  const int c4 = t % 144;
  const int pix2 = t / 144;          // (img, y-pair, x)
  const int x = pix2 & 127;
  const int yp = (pix2 >> 7) & 63;
  const int img = pix2 >> 13;
  const int y0 = yp * 2;

  float4 wt[3][3];
#pragma unroll
  for (int i = 0; i < 3; ++i)
#pragma unroll
    for (int j = 0; j < 3; ++j)
      wt[i][j] = *(const float4*)&wdw[(size_t)(i * 3 + j) * C3 + c4 * 4];

  float4 tap[4][3];
  const bool interior = ((unsigned)(x - 1) < 126u) && ((unsigned)(yp - 1) < 62u);
  if (interior) {
    const unsigned short* base = &in[((size_t)(img << 14) + (y0 << 7) + x) * C3 + c4 * 4];
#pragma unroll
    for (int i = 0; i < 4; ++i)
#pragma unroll
      for (int j = 0; j < 3; ++j)
        tap[i][j] = ld_bf4(&base[(ptrdiff_t)((i - 1) * 128 + (j - 1)) * C3]);
  } else {
#pragma unroll
    for (int i = 0; i < 4; ++i) {
      const int ry = y0 - 1 + i;
      const int ryc = ry < 0 ? 0 : (ry > 127 ? 127 : ry);
      const bool vy = (unsigned)ry < 128u;
#pragma unroll
      for (int j = 0; j < 3; ++j) {
        const int rx = x - 1 + j;
        const int rxc = rx < 0 ? 0 : (rx > 127 ? 127 : rx);
        float4 v = ld_bf4(&in[((size_t)(img << 14) + (ryc << 7) + rxc) * C3 + c4 * 4]);
        if (!(vy && ((unsigned)rx < 128u))) v = make_float4(0.f, 0.f, 0.f, 0.f);
        tap[i][j] = v;
      }
    }
  }

  float4 out0 = make_float4(0.f, 0.f, 0.f, 0.f);
  float4 out1 = make_float4(0.f, 0.f, 0.f, 0.f);
#pragma unroll
  for (int i = 0; i < 3; ++i)
#pragma unroll
    for (int j = 0; j < 3; ++j) {
      const float4 w = wt[i][j];
      const float4 a = tap[i][j];
      const float4 b = tap[i + 1][j];
      out0.x += a.x * w.x; out0.y += a.y * w.y; out0.z += a.z * w.z; out0.w += a.w * w.w;
      out1.x += b.x * w.x; out1.y += b.y * w.y; out1.z += b.z * w.z; out1.w += b.w * w.w;
    }

  const int p0 = (img << 14) + (y0 << 7) + x;
  const int p1 = p0 + 128;
  const float v0[4] = {out0.x, out0.y, out0.z, out0.w};
  const float v1[4] = {out1.x, out1.y, out1.z, out1.w};
  ushort4 a, b;
  unsigned short* ap = (unsigned short*)&a;
  unsigned short* bp = (unsigned short*)&b;
#pragma unroll
  for (int j = 0; j < 4; ++j) {
    ap[j] = f2bf(v0[j]);
    bp[j] = f2bf(v1[j]);
  }
  if (c4 < 96) {
    // q (c4<48) -> cols c4*4..; k (48<=c4<96) -> cols 192+(c4-48)*4 == c4*4
    *(ushort4*)&qk[(size_t)p0 * 384 + c4 * 4] = a;
    *(ushort4*)&qk[(size_t)p1 * 384 + c4 * 4] = b;
  } else {
    const int cc = (c4 - 96) * 4;
    *(ushort4*)&vh[(size_t)p0 * 192 + cc] = a;
    *(ushort4*)&vh[(size_t)p1 * 192 + cc] = b;
  }
}

// ------- Gram v4 (MFMA, single-pass bf16): G = Q^T K per (img,h); + ssq -----
// qk bf16 [npix][384]: q = cols 0..191, k = cols 192..383.
// LDS: u32-packed PAIRS of channels, [128 rows][W=50]: q uints 0..23, k 24..47.
__global__ __launch_bounds__(256) void gram48_v4(const unsigned short* __restrict__ qk,
                                                 float* __restrict__ G,
                                                 float* __restrict__ ssqq,
                                                 float* __restrict__ ssqk) {
  constexpr int W = 50;
  __shared__ unsigned int smem[9216];   // staging uses 128*50=6400; reduce uses 9216
  const int tid = threadIdx.x;
  const int lane = tid & 63;
  const int wv = tid >> 6;
  const int pair = blockIdx.y;          // img*4 + h
  const int img = pair >> 2, h = pair & 3;

  f32x4 acc[3][3] = {};
  float ssq_acc = 0.f;
  const int sch = tid % 96;
  const int shalf = tid / 96;

  for (int rnd = 0; rnd < 2; ++rnd) {
    const int sbase = (img << 14) + blockIdx.x * 256 + rnd * 128;
#pragma unroll
    for (int r = 0; r < 6; ++r) {
      const int idx = tid + (r << 8);    // 0..1535 = 128 rows x 12 uint4
      const int row = idx / 12, part = idx % 12;
      const bool isq = part < 6;
      const int sub = isq ? part : part - 6;
      const uint4 v = *(const uint4*)&qk[(size_t)(sbase + row) * 384 + (isq ? 0 : 192) + h * 48 + sub * 8];
      *(uint4*)&smem[row * W + (isq ? 0 : 24) + sub * 4] = v;
    }
    __syncthreads();
    {
      const int s0 = wv * 32 + ((lane >> 4) << 3);
      const int cm = lane & 15;
      const int half = cm & 1;
      bf16x8 qf[3], kf[3];
#pragma unroll
      for (int t3 = 0; t3 < 3; ++t3) {
        const int qc = t3 * 8 + (cm >> 1);
#pragma unroll
        for (int j = 0; j < 8; ++j) {
          const unsigned uq = smem[(s0 + j) * W + qc];
          const unsigned uk = smem[(s0 + j) * W + 24 + qc];
          qf[t3][j] = (short)(half ? (uq >> 16) : (uq & 0xffffu));
          kf[t3][j] = (short)(half ? (uk >> 16) : (uk & 0xffffu));
        }
      }
#pragma unroll
      for (int mt = 0; mt < 3; ++mt)
#pragma unroll
        for (int nt = 0; nt < 3; ++nt)
          acc[mt][nt] = __builtin_amdgcn_mfma_f32_16x16x32_bf16(qf[mt], kf[nt], acc[mt][nt], 0, 0, 0);
    }
    if (tid < 192) {
      const int cu = (sch < 48) ? (sch >> 1) : 24 + ((sch - 48) >> 1);
      const int hf = sch & 1;
      const int sstart = shalf * 64;
#pragma unroll 4
      for (int s = 0; s < 64; ++s) {
        const unsigned u = smem[(sstart + s) * W + cu];
        const float v = bf2f((unsigned short)(hf ? (u >> 16) : (u & 0xffffu)));
        ssq_acc += v * v;
      }
    }
    __syncthreads();
  }

  // block reduce 4 wave-partials (reuse smem as floats), then atomics
  float* red = (float*)smem;
  const int col = lane & 15;
  const int rbase = (lane >> 4) * 4;
#pragma unroll
  for (int mt = 0; mt < 3; ++mt)
#pragma unroll
    for (int nt = 0; nt < 3; ++nt)
#pragma unroll
      for (int rg = 0; rg < 4; ++rg)
        red[wv * 2304 + (mt * 16 + rbase + rg) * 48 + nt * 16 + col] = acc[mt][nt][rg];
  __syncthreads();
  float* Gm = &G[(size_t)pair * 2304];
#pragma unroll
  for (int c = 0; c < 9; ++c) {
    const int cell = tid + (c << 8);
    const float s4 = red[cell] + red[2304 + cell] + red[4608 + cell] + red[6912 + cell];
    atomicAdd(&Gm[cell], s4);
  }
  if (tid < 192) {
    if (sch < 48) atomicAdd(&ssqq[img * 192 + h * 48 + sch], ssq_acc);
    else          atomicAdd(&ssqk[img * 192 + h * 48 + sch - 48], ssq_acc);
  }
}

// ---- softmax over d of G*temp/(|q||k|), one wave per (img,h,row) -----------
__global__ __launch_bounds__(64) void attn_softmax(const float* __restrict__ G,
                                                   const float* __restrict__ ssqq,
                                                   const float* __restrict__ ssqk,
                                                   const float* __restrict__ temp,
                                                   float* __restrict__ attn) {
  const int r = blockIdx.x;          // 0..47
  const int h = blockIdx.y & 3;
  const int img = blockIdx.y >> 2;
  const int lane = threadIdx.x;
  const size_t base = (size_t)(img * 4 + h) * 2304;
  const float t = temp[h];
  const float qn = ssqq[img * 192 + h * CH + r];
  float val = -1e30f;
  if (lane < 48) {
    const float kn = ssqk[img * 192 + h * CH + lane];
    val = G[base + r * 48 + lane] * t * rsqrtf(qn * kn);
  }
  float m = val;
#pragma unroll
  for (int off = 32; off; off >>= 1) m = fmaxf(m, __shfl_xor(m, off));
  const float e = (lane < 48) ? expf(val - m) : 0.f;
  float ssum = e;
#pragma unroll
  for (int off = 32; off; off >>= 1) ssum += __shfl_xor(ssum, off);
  if (lane < 48) attn[base + r * 48 + lane] = e / ssum;
}

// ---- W_eff^T[img][n][D] = sum_c' A[img][h(D)][c'][D%48] * Wp[48h+c'][n] ----
__global__ __launch_bounds__(256) void make_weff(const float* __restrict__ attn,
                                                 const float* __restrict__ wproj,
                                                 unsigned short* __restrict__ weh,
                                                 unsigned short* __restrict__ wel) {
  const int t = blockIdx.x * 256 + threadIdx.x;   // over 4*192*192
  const int img = t / 36864;
  const int r = t % 36864;
  const int n = r / 192;
  const int D = r % 192;
  const int h = D / 48, dd = D % 48;
  const float* A = &attn[(size_t)(img * 4 + h) * 2304 + dd];
  const float* Wp = &wproj[(size_t)(h * 48) * 192 + n];
  float acc = 0.f;
#pragma unroll
  for (int c = 0; c < 48; ++c) acc += A[c * 48] * Wp[c * 192];
  const unsigned short hb = f2bf(acc);
  weh[(size_t)img * 36864 + n * 192 + D] = hb;
  wel[(size_t)img * 36864 + n * 192 + D] = f2bf(acc - bf2f(hb));
}

}  // namespace

extern "C" void kernel_launch(void* const* d_in, const int* in_sizes, int n_in,
                              void* d_out, int out_size, void* d_ws, size_t ws_size,
                              hipStream_t stream) {
  const float* x      = (const float*)d_in[0];
  const float* w_qkv  = (const float*)d_in[1];
  const float* w_dw   = (const float*)d_in[2];
  const float* w_proj = (const float*)d_in[3];
  const float* temp   = (const float*)d_in[4];
  float* out = (float*)d_out;

  // NI images per pass. NI=4 ≈ 178 MB (bf16 qk), fits the 256 MiB ws.
  auto layout_bytes = [](int NI) -> size_t {
    return (size_t)NI * HW * 576 * 2       // qkv bf16
         + (size_t)NI * HW * 384 * 2       // qk bf16
         + (size_t)NI * HW * 192 * 2       // vh (bf16)
         + (size_t)4 * HW * 192 * 2        // xh (all 4 images)
         + 2 * 221184                      // wqh, wql
         + 153600                          // G, ssqq, ssqk (all 4 images)
         + 147456                          // attnb (all 4 images)
         + 2 * 294912;                     // weh, wel (all 4 images)
  };
  const int NI = (ws_size >= layout_bytes(4)) ? 4 : ((ws_size >= layout_bytes(2)) ? 2 : 1);
  const int npass = 4 / NI;
  const int npix = NI * HW;

  char* p = (char*)d_ws;
  unsigned short* qkv = (unsigned short*)p; p += (size_t)npix * 576 * 2;
  unsigned short* qk = (unsigned short*)p;  p += (size_t)npix * 384 * 2;
  unsigned short* vh = (unsigned short*)p;  p += (size_t)npix * 192 * 2;
  unsigned short* xh = (unsigned short*)p;  p += (size_t)4 * HW * 192 * 2;
  unsigned short* wqh = (unsigned short*)p; p += 221184;
  unsigned short* wql = (unsigned short*)p; p += 221184;
  float* G    = (float*)p;           p += 147456;   // 16 (img,h) pairs
  float* ssqq = (float*)p;           p += 3072;     // 4 img x 192
  float* ssqk = (float*)p;           p += 3072;
  float* attnb = (float*)p;          p += 147456;
  unsigned short* weh = (unsigned short*)p; p += 294912;
  unsigned short* wel = (unsigned short*)p;

  cvt_wqkv<<<432, 256, 0, stream>>>(w_qkv, wqh, wql);
  cvt_x<<<4 * HW * 192 / 1024, 256, 0, stream>>>(x, xh);
  hipMemsetAsync(G, 0, 153600, stream);  // G+ssqq+ssqk, all 4 images, once

  for (int pass = 0; pass < npass; ++pass) {
    const size_t arow = (size_t)pass * npix * 192;
    float* outb = out + (size_t)pass * npix * C;
    float* Gp    = G + (size_t)pass * NI * 4 * 2304;
    float* sqp   = ssqq + (size_t)pass * NI * 192;
    float* skp   = ssqk + (size_t)pass * NI * 192;
    float* ap    = attnb + (size_t)pass * NI * 4 * 2304;
    unsigned short* wehp = weh + (size_t)pass * NI * 36864;
    unsigned short* welp = wel + (size_t)pass * NI * 36864;
    gemm_mfma<576, false, true><<<dim3(npix / 128, 9), 256, 0, stream>>>(
        xh + arow, wqh, wql, qkv);
    dwconv3x3_v4<<<npix * 72 / 256, 256, 0, stream>>>(qkv, w_dw, qk, vh);
    gram48_v4<<<dim3(64, 4 * NI), 256, 0, stream>>>(qk, Gp, sqp, skp);
    attn_softmax<<<dim3(48, 4 * NI), 64, 0, stream>>>(Gp, sqp, skp, temp, ap);
    make_weff<<<NI * 144, 256, 0, stream>>>(ap, w_proj, wehp, welp);
    gemm_mfma<192, true, false><<<dim3(npix / 128, 3), 256, 0, stream>>>(
        vh, wehp, welp, outb);
  }
}

// Round 12
// 163.692 us; speedup vs baseline: 1.5299x; 1.0728x over previous
//
#include <hip/hip_runtime.h>

namespace {

constexpr int HW = 16384;   // pixels per image
constexpr int C  = 192;
constexpr int C3 = 576;
constexpr int CH = 48;
constexpr int K  = 192;

using bf16x8 = __attribute__((ext_vector_type(8))) short;
using f32x4  = __attribute__((ext_vector_type(4))) float;

__device__ inline unsigned short f2bf(float f) {
  unsigned u = __float_as_uint(f);
  unsigned r = (u + 0x7fff + ((u >> 16) & 1)) >> 16;
  return (unsigned short)r;
}
__device__ inline float bf2f(unsigned short b) {
  return __uint_as_float(((unsigned)b) << 16);
}
__device__ inline float4 ld_bf4(const unsigned short* p) {
  const ushort4 u = *(const ushort4*)p;
  return make_float4(bf2f(u.x), bf2f(u.y), bf2f(u.z), bf2f(u.w));
}

// async global->LDS, 16B per lane. LDS dest = wave-uniform base + lane*16.
__device__ __forceinline__ void ld_g2l16(const unsigned short* g, unsigned short* l) {
  __builtin_amdgcn_global_load_lds(
      (const __attribute__((address_space(1))) unsigned int*)(unsigned long long)(const void*)g,
      (__attribute__((address_space(3))) unsigned int*)(unsigned int)(unsigned long long)(void*)l,
      16, 0, 0);
}

// ---- transpose + split qkv weights: [192,576] -> hi/lo [576][192] ----------
__global__ __launch_bounds__(256) void cvt_wqkv(const float* __restrict__ wqkv,
                                                unsigned short* __restrict__ wqh,
                                                unsigned short* __restrict__ wql) {
  const int t = blockIdx.x * 256 + threadIdx.x;  // 0 .. 576*192-1
  const int n = t / 192;
  const int k = t % 192;
  const float v = wqkv[k * C3 + n];
  const unsigned short h = f2bf(v);
  wqh[n * 192 + k] = h;
  wql[n * 192 + k] = f2bf(v - bf2f(h));
}

// ---- MFMA GEMM: Co[M,N] = A[M,192] @ (Bh+Bl)[N,192]^T, 2-pass bf16 ---------
// CVTA: A is fp32, converted rne->bf16 during reg-staging (ds_write, swizzled).
// OBF16: emit bf16 output (qkv path); else fp32 (final out).
template <int N, bool PERB, bool OBF16, bool CVTA>
__global__ __launch_bounds__(256, 4) void gemm_mfma(const void* __restrict__ Ap,
                                                    const unsigned short* __restrict__ Bh,
                                                    const unsigned short* __restrict__ Bl,
                                                    void* __restrict__ Co) {
  __shared__ __align__(16) unsigned short sAh[2][128 * 32];
  __shared__ __align__(16) unsigned short sBh[2][64 * 32];
  __shared__ __align__(16) unsigned short sBl[2][64 * 32];
  const int t = threadIdx.x;
  const int lane = t & 63;
  const int wv = t >> 6;
  const int m0 = blockIdx.x * 128;
  const int n0 = blockIdx.y * 64;
  const size_t boff = PERB ? (size_t)(m0 >> 14) * (192 * 192) : 0;
  const int wr = wv >> 1, wc = wv & 1;
  const int fr_row = lane & 15;
  const int fr_swz = ((lane >> 4) ^ (lane & 3)) << 3;

  // staging geometry: LDS[row][phys_slot] holds logical slot phys^(row&3)
  const int arow0 = wv * 32;           // A rows per wave: 2 issues of 16 rows
  const int lrow  = lane >> 2;
  const int lslot = lane & 3;
  const int brow0 = wv * 16;           // B rows per wave: 1 issue

  f32x4 acc[4][2] = {};

  auto stage = [&](int buf, int k0) {
#pragma unroll
    for (int r = 0; r < 2; ++r) {
      const int row = arow0 + r * 16 + lrow;
      const int ssl = lslot ^ (row & 3);
      if constexpr (CVTA) {
        const float* src = &((const float*)Ap)[(size_t)(m0 + row) * K + k0 + (lslot << 3)];
        const float4 f0 = *(const float4*)src;
        const float4 f1 = *(const float4*)(src + 4);
        bf16x8 h;
        h[0] = (short)f2bf(f0.x); h[1] = (short)f2bf(f0.y);
        h[2] = (short)f2bf(f0.z); h[3] = (short)f2bf(f0.w);
        h[4] = (short)f2bf(f1.x); h[5] = (short)f2bf(f1.y);
        h[6] = (short)f2bf(f1.z); h[7] = (short)f2bf(f1.w);
        *(bf16x8*)&sAh[buf][row * 32 + (ssl << 3)] = h;
      } else {
        const size_t go = (size_t)(m0 + row) * K + k0 + (ssl << 3);
        ld_g2l16(&((const unsigned short*)Ap)[go], &sAh[buf][(arow0 + r * 16) * 32]);
      }
    }
    {
      const int row = brow0 + lrow;
      const int ssl = lslot ^ (row & 3);
      const size_t go = boff + (size_t)(n0 + row) * K + k0 + (ssl << 3);
      ld_g2l16(&Bh[go], &sBh[buf][brow0 * 32]);
      ld_g2l16(&Bl[go], &sBl[buf][brow0 * 32]);
    }
  };

  stage(0, 0);
  __syncthreads();
#pragma unroll
  for (int ks = 0; ks < 6; ++ks) {
    if (ks < 5) stage((ks + 1) & 1, (ks + 1) * 32);
    const int buf = ks & 1;
    bf16x8 fah[4], fbh[2], fbl[2];
#pragma unroll
    for (int i = 0; i < 4; ++i) {
      const int row = wr * 64 + i * 16 + fr_row;
      fah[i] = *(const bf16x8*)&sAh[buf][row * 32 + fr_swz];
    }
#pragma unroll
    for (int j = 0; j < 2; ++j) {
      const int row = wc * 32 + j * 16 + fr_row;
      fbh[j] = *(const bf16x8*)&sBh[buf][row * 32 + fr_swz];
      fbl[j] = *(const bf16x8*)&sBl[buf][row * 32 + fr_swz];
    }
#pragma unroll
    for (int i = 0; i < 4; ++i)
#pragma unroll
      for (int j = 0; j < 2; ++j) {
        acc[i][j] = __builtin_amdgcn_mfma_f32_16x16x32_bf16(fah[i], fbh[j], acc[i][j], 0, 0, 0);
        acc[i][j] = __builtin_amdgcn_mfma_f32_16x16x32_bf16(fah[i], fbl[j], acc[i][j], 0, 0, 0);
      }
    if (ks < 5) __syncthreads();
  }

  const int er = (lane >> 4) << 2;  // C/D: col=lane&15, row=(lane>>4)*4+reg
  const int ec = lane & 15;
#pragma unroll
  for (int i = 0; i < 4; ++i)
#pragma unroll
    for (int j = 0; j < 2; ++j) {
      const size_t base = (size_t)(m0 + wr * 64 + i * 16 + er) * N + n0 + wc * 32 + j * 16 + ec;
      if constexpr (OBF16) {
        unsigned short* cp = (unsigned short*)Co + base;
#pragma unroll
        for (int r = 0; r < 4; ++r) cp[(size_t)r * N] = f2bf(acc[i][j][r]);
      } else {
        float* cp = (float*)Co + base;
#pragma unroll
        for (int r = 0; r < 4; ++r) cp[(size_t)r * N] = acc[i][j][r];
      }
    }
}

// ---- depthwise 3x3 SAME, rolling-window TY=8, bf16 in/out ------------------
// q,k -> bf16 qk[p][384]; v -> bf16 vh[p][192]
constexpr int TY = 8;
__global__ __launch_bounds__(256) void dwconv3x3_v5(const unsigned short* __restrict__ in,
                                                    const float* __restrict__ wdw,
                                                    unsigned short* __restrict__ qk,
                                                    unsigned short* __restrict__ vh) {
  const int t = blockIdx.x * 256 + threadIdx.x;
  const int c4 = t % 144;
  const int rest = t / 144;          // (img, ystrip, x)
  const int x = rest & 127;
  const int ys = (rest >> 7) & 15;   // 16 strips of TY=8
  const int img = rest >> 11;
  const int y0 = ys * TY;

  float4 wt[3][3];
#pragma unroll
  for (int i = 0; i < 3; ++i)
#pragma unroll
    for (int j = 0; j < 3; ++j)
      wt[i][j] = *(const float4*)&wdw[(size_t)(i * 3 + j) * C3 + c4 * 4];

  const bool xm = x > 0, xp = x < 127;
  const unsigned short* ibase = &in[((size_t)((img << 14) + x)) * C3 + c4 * 4];
  const float4 z4 = make_float4(0.f, 0.f, 0.f, 0.f);
  const ptrdiff_t dxm = xm ? -(ptrdiff_t)C3 : 0;   // clamped ptr + select-zero
  const ptrdiff_t dxp = xp ? (ptrdiff_t)C3 : 0;

  auto ldrow = [&](int yy, float4* r) {
    if ((unsigned)yy < 128u) {
      const unsigned short* rp = ibase + (size_t)yy * (128 * C3);
      float4 a = ld_bf4(rp + dxm);
      float4 m = ld_bf4(rp);
      float4 b = ld_bf4(rp + dxp);
      if (!xm) a = z4;
      if (!xp) b = z4;
      r[0] = a; r[1] = m; r[2] = b;
    } else {
      r[0] = z4; r[1] = z4; r[2] = z4;
    }
  };

  float4 r0[3], r1[3], r2[3], rn[3];
  ldrow(y0 - 1, r0);
  ldrow(y0, r1);
  ldrow(y0 + 1, r2);

#pragma unroll
  for (int i = 0; i < TY; ++i) {
    if (i < TY - 1) ldrow(y0 + i + 2, rn);  // prefetch overlaps compute below
    float4 o = z4;
#pragma unroll
    for (int j = 0; j < 3; ++j) {
      o.x += r0[j].x * wt[0][j].x; o.y += r0[j].y * wt[0][j].y;
      o.z += r0[j].z * wt[0][j].z; o.w += r0[j].w * wt[0][j].w;
      o.x += r1[j].x * wt[1][j].x; o.y += r1[j].y * wt[1][j].y;
      o.z += r1[j].z * wt[1][j].z; o.w += r1[j].w * wt[1][j].w;
      o.x += r2[j].x * wt[2][j].x; o.y += r2[j].y * wt[2][j].y;
      o.z += r2[j].z * wt[2][j].z; o.w += r2[j].w * wt[2][j].w;
    }
    const int p = (img << 14) + ((y0 + i) << 7) + x;
    const ushort4 ob = make_ushort4(f2bf(o.x), f2bf(o.y), f2bf(o.z), f2bf(o.w));
    if (c4 < 96) *(ushort4*)&qk[(size_t)p * 384 + c4 * 4] = ob;
    else         *(ushort4*)&vh[(size_t)p * 192 + (c4 - 96) * 4] = ob;
    if (i < TY - 1) {
#pragma unroll
      for (int j = 0; j < 3; ++j) { r0[j] = r1[j]; r1[j] = r2[j]; r2[j] = rn[j]; }
    }
  }
}

// ------- Gram v4 (MFMA, single-pass bf16): G = Q^T K per (img,h); + ssq -----
// qk bf16 [npix][384]: q = cols 0..191, k = cols 192..383.
// LDS: u32-packed PAIRS of channels, [128 rows][W=50]: q uints 0..23, k 24..47.
__global__ __launch_bounds__(256) void gram48_v4(const unsigned short* __restrict__ qk,
                                                 float* __restrict__ G,
                                                 float* __restrict__ ssqq,
                                                 float* __restrict__ ssqk) {
  constexpr int W = 50;
  __shared__ unsigned int smem[9216];   // staging uses 128*50=6400; reduce uses 9216
  const int tid = threadIdx.x;
  const int lane = tid & 63;
  const int wv = tid >> 6;
  const int pair = blockIdx.y;          // img*4 + h
  const int img = pair >> 2, h = pair & 3;

  f32x4 acc[3][3] = {};
  float ssq_acc = 0.f;
  const int sch = tid % 96;
  const int shalf = tid / 96;

  for (int rnd = 0; rnd < 2; ++rnd) {
    const int sbase = (img << 14) + blockIdx.x * 256 + rnd * 128;
#pragma unroll
    for (int r = 0; r < 6; ++r) {
      const int idx = tid + (r << 8);    // 0..1535 = 128 rows x 12 uint4
      const int row = idx / 12, part = idx % 12;
      const bool isq = part < 6;
      const int sub = isq ? part : part - 6;
      const uint4 v = *(const uint4*)&qk[(size_t)(sbase + row) * 384 + (isq ? 0 : 192) + h * 48 + sub * 8];
      *(uint4*)&smem[row * W + (isq ? 0 : 24) + sub * 4] = v;
    }
    __syncthreads();
    {
      const int s0 = wv * 32 + ((lane >> 4) << 3);
      const int cm = lane & 15;
      const int half = cm & 1;
      bf16x8 qf[3], kf[3];
#pragma unroll
      for (int t3 = 0; t3 < 3; ++t3) {
        const int qc = t3 * 8 + (cm >> 1);
#pragma unroll
        for (int j = 0; j < 8; ++j) {
          const unsigned uq = smem[(s0 + j) * W + qc];
          const unsigned uk = smem[(s0 + j) * W + 24 + qc];
          qf[t3][j] = (short)(half ? (uq >> 16) : (uq & 0xffffu));
          kf[t3][j] = (short)(half ? (uk >> 16) : (uk & 0xffffu));
        }
      }
#pragma unroll
      for (int mt = 0; mt < 3; ++mt)
#pragma unroll
        for (int nt = 0; nt < 3; ++nt)
          acc[mt][nt] = __builtin_amdgcn_mfma_f32_16x16x32_bf16(qf[mt], kf[nt], acc[mt][nt], 0, 0, 0);
    }
    if (tid < 192) {
      const int cu = (sch < 48) ? (sch >> 1) : 24 + ((sch - 48) >> 1);
      const int hf = sch & 1;
      const int sstart = shalf * 64;
#pragma unroll 4
      for (int s = 0; s < 64; ++s) {
        const unsigned u = smem[(sstart + s) * W + cu];
        const float v = bf2f((unsigned short)(hf ? (u >> 16) : (u & 0xffffu)));
        ssq_acc += v * v;
      }
    }
    __syncthreads();
  }

  // block reduce 4 wave-partials (reuse smem as floats), then atomics
  float* red = (float*)smem;
  const int col = lane & 15;
  const int rbase = (lane >> 4) * 4;
#pragma unroll
  for (int mt = 0; mt < 3; ++mt)
#pragma unroll
    for (int nt = 0; nt < 3; ++nt)
#pragma unroll
      for (int rg = 0; rg < 4; ++rg)
        red[wv * 2304 + (mt * 16 + rbase + rg) * 48 + nt * 16 + col] = acc[mt][nt][rg];
  __syncthreads();
  float* Gm = &G[(size_t)pair * 2304];
#pragma unroll
  for (int c = 0; c < 9; ++c) {
    const int cell = tid + (c << 8);
    const float s4 = red[cell] + red[2304 + cell] + red[4608 + cell] + red[6912 + cell];
    atomicAdd(&Gm[cell], s4);
  }
  if (tid < 192) {
    if (sch < 48) atomicAdd(&ssqq[img * 192 + h * 48 + sch], ssq_acc);
    else          atomicAdd(&ssqk[img * 192 + h * 48 + sch - 48], ssq_acc);
  }
}

// ---- softmax over d of G*temp/(|q||k|), one wave per (img,h,row) -----------
__global__ __launch_bounds__(64) void attn_softmax(const float* __restrict__ G,
                                                   const float* __restrict__ ssqq,
                                                   const float* __restrict__ ssqk,
                                                   const float* __restrict__ temp,
                                                   float* __restrict__ attn) {
  const int r = blockIdx.x;          // 0..47
  const int h = blockIdx.y & 3;
  const int img = blockIdx.y >> 2;
  const int lane = threadIdx.x;
  const size_t base = (size_t)(img * 4 + h) * 2304;
  const float t = temp[h];
  const float qn = ssqq[img * 192 + h * CH + r];
  float val = -1e30f;
  if (lane < 48) {
    const float kn = ssqk[img * 192 + h * CH + lane];
    val = G[base + r * 48 + lane] * t * rsqrtf(qn * kn);
  }
  float m = val;
#pragma unroll
  for (int off = 32; off; off >>= 1) m = fmaxf(m, __shfl_xor(m, off));
  const float e = (lane < 48) ? expf(val - m) : 0.f;
  float ssum = e;
#pragma unroll
  for (int off = 32; off; off >>= 1) ssum += __shfl_xor(ssum, off);
  if (lane < 48) attn[base + r * 48 + lane] = e / ssum;
}

// ---- W_eff^T[img][n][D] = sum_c' A[img][h(D)][c'][D%48] * Wp[48h+c'][n] ----
__global__ __launch_bounds__(256) void make_weff(const float* __restrict__ attn,
                                                 const float* __restrict__ wproj,
                                                 unsigned short* __restrict__ weh,
                                                 unsigned short* __restrict__ wel) {
  const int t = blockIdx.x * 256 + threadIdx.x;   // over 4*192*192
  const int img = t / 36864;
  const int r = t % 36864;
  const int n = r / 192;
  const int D = r % 192;
  const int h = D / 48, dd = D % 48;
  const float* A = &attn[(size_t)(img * 4 + h) * 2304 + dd];
  const float* Wp = &wproj[(size_t)(h * 48) * 192 + n];
  float acc = 0.f;
#pragma unroll
  for (int c = 0; c < 48; ++c) acc += A[c * 48] * Wp[c * 192];
  const unsigned short hb = f2bf(acc);
  weh[(size_t)img * 36864 + n * 192 + D] = hb;
  wel[(size_t)img * 36864 + n * 192 + D] = f2bf(acc - bf2f(hb));
}

}  // namespace

extern "C" void kernel_launch(void* const* d_in, const int* in_sizes, int n_in,
                              void* d_out, int out_size, void* d_ws, size_t ws_size,
                              hipStream_t stream) {
  const float* x      = (const float*)d_in[0];
  const float* w_qkv  = (const float*)d_in[1];
  const float* w_dw   = (const float*)d_in[2];
  const float* w_proj = (const float*)d_in[3];
  const float* temp   = (const float*)d_in[4];
  float* out = (float*)d_out;

  // NI images per pass. NI=4 ≈ 128 MB (no xh buffer), fits the 256 MiB ws.
  auto layout_bytes = [](int NI) -> size_t {
    return (size_t)NI * HW * 576 * 2       // qkv bf16
         + (size_t)NI * HW * 384 * 2       // qk bf16
         + (size_t)NI * HW * 192 * 2       // vh (bf16)
         + 2 * 221184                      // wqh, wql
         + 153600                          // G, ssqq, ssqk (all 4 images)
         + 147456                          // attnb (all 4 images)
         + 2 * 294912;                     // weh, wel (all 4 images)
  };
  const int NI = (ws_size >= layout_bytes(4)) ? 4 : ((ws_size >= layout_bytes(2)) ? 2 : 1);
  const int npass = 4 / NI;
  const int npix = NI * HW;

  char* p = (char*)d_ws;
  unsigned short* qkv = (unsigned short*)p; p += (size_t)npix * 576 * 2;
  unsigned short* qk = (unsigned short*)p;  p += (size_t)npix * 384 * 2;
  unsigned short* vh = (unsigned short*)p;  p += (size_t)npix * 192 * 2;
  unsigned short* wqh = (unsigned short*)p; p += 221184;
  unsigned short* wql = (unsigned short*)p; p += 221184;
  float* G    = (float*)p;           p += 147456;   // 16 (img,h) pairs
  float* ssqq = (float*)p;           p += 3072;     // 4 img x 192
  float* ssqk = (float*)p;           p += 3072;
  float* attnb = (float*)p;          p += 147456;
  unsigned short* weh = (unsigned short*)p; p += 294912;
  unsigned short* wel = (unsigned short*)p;

  cvt_wqkv<<<432, 256, 0, stream>>>(w_qkv, wqh, wql);
  hipMemsetAsync(G, 0, 153600, stream);  // G+ssqq+ssqk, all 4 images, once

  for (int pass = 0; pass < npass; ++pass) {
    const float* xb = x + (size_t)pass * npix * K;
    float* outb = out + (size_t)pass * npix * C;
    float* Gp    = G + (size_t)pass * NI * 4 * 2304;
    float* sqp   = ssqq + (size_t)pass * NI * 192;
    float* skp   = ssqk + (size_t)pass * NI * 192;
    float* ap    = attnb + (size_t)pass * NI * 4 * 2304;
    unsigned short* wehp = weh + (size_t)pass * NI * 36864;
    unsigned short* welp = wel + (size_t)pass * NI * 36864;
    gemm_mfma<576, false, true, true><<<dim3(npix / 128, 9), 256, 0, stream>>>(
        xb, wqh, wql, qkv);
    dwconv3x3_v5<<<npix * 144 / TY / 256, 256, 0, stream>>>(qkv, w_dw, qk, vh);
    gram48_v4<<<dim3(64, 4 * NI), 256, 0, stream>>>(qk, Gp, sqp, skp);
    attn_softmax<<<dim3(48, 4 * NI), 64, 0, stream>>>(Gp, sqp, skp, temp, ap);
    make_weff<<<NI * 144, 256, 0, stream>>>(ap, w_proj, wehp, welp);
    gemm_mfma<192, true, false, false><<<dim3(npix / 128, 3), 256, 0, stream>>>(
        vh, wehp, welp, outb);
  }
}

// Round 13
// 135.065 us; speedup vs baseline: 1.8542x; 1.2120x over previous
//
#include <hip/hip_runtime.h>

namespace {

constexpr int HW = 16384;   // pixels per image
constexpr int C  = 192;
constexpr int C3 = 576;
constexpr int CH = 48;
constexpr int K  = 192;

using bf16x8 = __attribute__((ext_vector_type(8))) short;
using f32x4  = __attribute__((ext_vector_type(4))) float;

__device__ inline unsigned short f2bf(float f) {
  unsigned u = __float_as_uint(f);
  unsigned r = (u + 0x7fff + ((u >> 16) & 1)) >> 16;
  return (unsigned short)r;
}
__device__ inline float bf2f(unsigned short b) {
  return __uint_as_float(((unsigned)b) << 16);
}
__device__ inline float4 ld_bf4(const unsigned short* p) {
  const ushort4 u = *(const ushort4*)p;
  return make_float4(bf2f(u.x), bf2f(u.y), bf2f(u.z), bf2f(u.w));
}

// async global->LDS, 16B per lane. LDS dest = wave-uniform base + lane*16.
__device__ __forceinline__ void ld_g2l16(const unsigned short* g, unsigned short* l) {
  __builtin_amdgcn_global_load_lds(
      (const __attribute__((address_space(1))) unsigned int*)(unsigned long long)(const void*)g,
      (__attribute__((address_space(3))) unsigned int*)(unsigned int)(unsigned long long)(void*)l,
      16, 0, 0);
}

// ---- transpose + split qkv weights: [192,576] -> hi/lo [576][192] ----------
__global__ __launch_bounds__(256) void cvt_wqkv(const float* __restrict__ wqkv,
                                                unsigned short* __restrict__ wqh,
                                                unsigned short* __restrict__ wql) {
  const int t = blockIdx.x * 256 + threadIdx.x;  // 0 .. 576*192-1
  const int n = t / 192;
  const int k = t % 192;
  const float v = wqkv[k * C3 + n];
  const unsigned short h = f2bf(v);
  wqh[n * 192 + k] = h;
  wql[n * 192 + k] = f2bf(v - bf2f(h));
}

// ---- MFMA GEMM: Co[M, NT*64] = A[M,192] @ (Bh+Bl)[NT*64,192]^T, 2-pass -----
// One block = 128 rows x ALL n-tiles. A converted/staged ONCE into registers
// (fah[6][4], all static indices), then NT x 6 steps with B double-buffered.
// CVTA: A fp32 -> rne bf16 during staging (padded LDS stride 40 kills the
// 8-way ds_write conflict); else A bf16 via global_load_lds (linear, stride 32).
template <int NT, bool PERB, bool OBF16, bool CVTA>
__global__ __launch_bounds__(256) void gemm_mfma(const void* __restrict__ Ap,
                                                 const unsigned short* __restrict__ Bh,
                                                 const unsigned short* __restrict__ Bl,
                                                 void* __restrict__ Co) {
  constexpr int N = NT * 64;
  constexpr int AST = CVTA ? 40 : 32;   // A LDS row stride (ushorts)
  __shared__ __align__(16) unsigned short sA[128 * AST];
  __shared__ __align__(16) unsigned short sBh[2][64 * 32];
  __shared__ __align__(16) unsigned short sBl[2][64 * 32];
  const int t = threadIdx.x;
  const int lane = t & 63;
  const int wv = t >> 6;
  const int m0 = blockIdx.x * 128;
  const size_t boff = PERB ? (size_t)(m0 >> 14) * (192 * 192) : 0;
  const int wr = wv >> 1, wc = wv & 1;
  const int fr_row = lane & 15;
  const int fr_swz = ((lane >> 4) ^ (lane & 3)) << 3;
  const int arow0 = wv * 32;           // A staging rows per wave (2 issues x 16)
  const int lrow  = lane >> 2;
  const int lslot = lane & 3;
  const int brow0 = wv * 16;           // B staging rows per wave (1 issue)

  // ---- phase 1: A -> registers, staged k-step by k-step --------------------
  bf16x8 fah[6][4];
#pragma unroll
  for (int ks = 0; ks < 6; ++ks) {
    const int k0 = ks * 32;
#pragma unroll
    for (int r = 0; r < 2; ++r) {
      const int row = arow0 + r * 16 + lrow;
      const int ssl = lslot ^ (row & 3);
      if constexpr (CVTA) {
        const float* src = &((const float*)Ap)[(size_t)(m0 + row) * K + k0 + (lslot << 3)];
        const float4 f0 = *(const float4*)src;
        const float4 f1 = *(const float4*)(src + 4);
        bf16x8 h;
        h[0] = (short)f2bf(f0.x); h[1] = (short)f2bf(f0.y);
        h[2] = (short)f2bf(f0.z); h[3] = (short)f2bf(f0.w);
        h[4] = (short)f2bf(f1.x); h[5] = (short)f2bf(f1.y);
        h[6] = (short)f2bf(f1.z); h[7] = (short)f2bf(f1.w);
        *(bf16x8*)&sA[row * AST + (ssl << 3)] = h;
      } else {
        const size_t go = (size_t)(m0 + row) * K + k0 + (ssl << 3);
        ld_g2l16(&((const unsigned short*)Ap)[go], &sA[(arow0 + r * 16) * AST]);
      }
    }
    __syncthreads();
#pragma unroll
    for (int i = 0; i < 4; ++i) {
      const int row = wr * 64 + i * 16 + fr_row;
      fah[ks][i] = *(const bf16x8*)&sA[row * AST + fr_swz];
    }
    __syncthreads();
  }

  // ---- phase 2: n-tile loop, B double-buffered -----------------------------
  auto stageB = [&](int buf, int nt_, int ks_) {
    const int row = brow0 + lrow;
    const int ssl = lslot ^ (row & 3);
    const size_t go = boff + (size_t)(nt_ * 64 + row) * K + ks_ * 32 + (ssl << 3);
    ld_g2l16(&Bh[go], &sBh[buf][brow0 * 32]);
    ld_g2l16(&Bl[go], &sBl[buf][brow0 * 32]);
  };

  stageB(0, 0, 0);
  __syncthreads();
  const int er = (lane >> 4) << 2;  // C/D: col=lane&15, row=(lane>>4)*4+reg
  const int ec = lane & 15;
  for (int nt = 0; nt < NT; ++nt) {
    f32x4 acc[4][2] = {};
#pragma unroll
    for (int ks = 0; ks < 6; ++ks) {
      const bool last = (nt == NT - 1) && (ks == 5);
      if (!last) {
        if (ks < 5) stageB((ks + 1) & 1, nt, ks + 1);
        else        stageB(0, nt + 1, 0);
      }
      constexpr int bufsel[6] = {0, 1, 0, 1, 0, 1};
      const int buf = bufsel[ks];
      bf16x8 fbh[2], fbl[2];
#pragma unroll
      for (int j = 0; j < 2; ++j) {
        const int row = wc * 32 + j * 16 + fr_row;
        fbh[j] = *(const bf16x8*)&sBh[buf][row * 32 + fr_swz];
        fbl[j] = *(const bf16x8*)&sBl[buf][row * 32 + fr_swz];
      }
#pragma unroll
      for (int i = 0; i < 4; ++i)
#pragma unroll
        for (int j = 0; j < 2; ++j) {
          acc[i][j] = __builtin_amdgcn_mfma_f32_16x16x32_bf16(fah[ks][i], fbh[j], acc[i][j], 0, 0, 0);
          acc[i][j] = __builtin_amdgcn_mfma_f32_16x16x32_bf16(fah[ks][i], fbl[j], acc[i][j], 0, 0, 0);
        }
      if (!last) __syncthreads();
    }
#pragma unroll
    for (int i = 0; i < 4; ++i)
#pragma unroll
      for (int j = 0; j < 2; ++j) {
        const size_t base = (size_t)(m0 + wr * 64 + i * 16 + er) * N + nt * 64 + wc * 32 + j * 16 + ec;
        if constexpr (OBF16) {
          unsigned short* cp = (unsigned short*)Co + base;
#pragma unroll
          for (int r = 0; r < 4; ++r) cp[(size_t)r * N] = f2bf(acc[i][j][r]);
        } else {
          float* cp = (float*)Co + base;
#pragma unroll
          for (int r = 0; r < 4; ++r) cp[(size_t)r * N] = acc[i][j][r];
        }
      }
  }
}

// ---- depthwise 3x3 SAME, rolling-window TY=8, bf16 in/out ------------------
// q,k -> bf16 qk[p][384]; v -> bf16 vh[p][192]
constexpr int TY = 8;
__global__ __launch_bounds__(256) void dwconv3x3_v5(const unsigned short* __restrict__ in,
                                                    const float* __restrict__ wdw,
                                                    unsigned short* __restrict__ qk,
                                                    unsigned short* __restrict__ vh) {
  const int t = blockIdx.x * 256 + threadIdx.x;
  const int c4 = t % 144;
  const int rest = t / 144;          // (img, ystrip, x)
  const int x = rest & 127;
  const int ys = (rest >> 7) & 15;   // 16 strips of TY=8
  const int img = rest >> 11;
  const int y0 = ys * TY;

  float4 wt[3][3];
#pragma unroll
  for (int i = 0; i < 3; ++i)
#pragma unroll
    for (int j = 0; j < 3; ++j)
      wt[i][j] = *(const float4*)&wdw[(size_t)(i * 3 + j) * C3 + c4 * 4];

  const bool xm = x > 0, xp = x < 127;
  const unsigned short* ibase = &in[((size_t)((img << 14) + x)) * C3 + c4 * 4];
  const float4 z4 = make_float4(0.f, 0.f, 0.f, 0.f);
  const ptrdiff_t dxm = xm ? -(ptrdiff_t)C3 : 0;   // clamped ptr + select-zero
  const ptrdiff_t dxp = xp ? (ptrdiff_t)C3 : 0;

  auto ldrow = [&](int yy, float4* r) {
    if ((unsigned)yy < 128u) {
      const unsigned short* rp = ibase + (size_t)yy * (128 * C3);
      float4 a = ld_bf4(rp + dxm);
      float4 m = ld_bf4(rp);
      float4 b = ld_bf4(rp + dxp);
      if (!xm) a = z4;
      if (!xp) b = z4;
      r[0] = a; r[1] = m; r[2] = b;
    } else {
      r[0] = z4; r[1] = z4; r[2] = z4;
    }
  };

  float4 r0[3], r1[3], r2[3], rn[3];
  ldrow(y0 - 1, r0);
  ldrow(y0, r1);
  ldrow(y0 + 1, r2);

#pragma unroll
  for (int i = 0; i < TY; ++i) {
    if (i < TY - 1) ldrow(y0 + i + 2, rn);  // prefetch overlaps compute below
    float4 o = z4;
#pragma unroll
    for (int j = 0; j < 3; ++j) {
      o.x += r0[j].x * wt[0][j].x; o.y += r0[j].y * wt[0][j].y;
      o.z += r0[j].z * wt[0][j].z; o.w += r0[j].w * wt[0][j].w;
      o.x += r1[j].x * wt[1][j].x; o.y += r1[j].y * wt[1][j].y;
      o.z += r1[j].z * wt[1][j].z; o.w += r1[j].w * wt[1][j].w;
      o.x += r2[j].x * wt[2][j].x; o.y += r2[j].y * wt[2][j].y;
      o.z += r2[j].z * wt[2][j].z; o.w += r2[j].w * wt[2][j].w;
    }
    const int p = (img << 14) + ((y0 + i) << 7) + x;
    const ushort4 ob = make_ushort4(f2bf(o.x), f2bf(o.y), f2bf(o.z), f2bf(o.w));
    if (c4 < 96) *(ushort4*)&qk[(size_t)p * 384 + c4 * 4] = ob;
    else         *(ushort4*)&vh[(size_t)p * 192 + (c4 - 96) * 4] = ob;
    if (i < TY - 1) {
#pragma unroll
      for (int j = 0; j < 3; ++j) { r0[j] = r1[j]; r1[j] = r2[j]; r2[j] = rn[j]; }
    }
  }
}

// ------- Gram v4 (MFMA, single-pass bf16): G = Q^T K per (img,h); + ssq -----
// qk bf16 [npix][384]: q = cols 0..191, k = cols 192..383.
// LDS: u32-packed PAIRS of channels, [128 rows][W=50]: q uints 0..23, k 24..47.
__global__ __launch_bounds__(256) void gram48_v4(const unsigned short* __restrict__ qk,
                                                 float* __restrict__ G,
                                                 float* __restrict__ ssqq,
                                                 float* __restrict__ ssqk) {
  constexpr int W = 50;
  __shared__ unsigned int smem[9216];   // staging uses 128*50=6400; reduce uses 9216
  const int tid = threadIdx.x;
  const int lane = tid & 63;
  const int wv = tid >> 6;
  const int pair = blockIdx.y;          // img*4 + h
  const int img = pair >> 2, h = pair & 3;

  f32x4 acc[3][3] = {};
  float ssq_acc = 0.f;
  const int sch = tid % 96;
  const int shalf = tid / 96;

  for (int rnd = 0; rnd < 2; ++rnd) {
    const int sbase = (img << 14) + blockIdx.x * 256 + rnd * 128;
#pragma unroll
    for (int r = 0; r < 6; ++r) {
      const int idx = tid + (r << 8);    // 0..1535 = 128 rows x 12 uint4
      const int row = idx / 12, part = idx % 12;
      const bool isq = part < 6;
      const int sub = isq ? part : part - 6;
      const uint4 v = *(const uint4*)&qk[(size_t)(sbase + row) * 384 + (isq ? 0 : 192) + h * 48 + sub * 8];
      *(uint4*)&smem[row * W + (isq ? 0 : 24) + sub * 4] = v;
    }
    __syncthreads();
    {
      const int s0 = wv * 32 + ((lane >> 4) << 3);
      const int cm = lane & 15;
      const int half = cm & 1;
      bf16x8 qf[3], kf[3];
#pragma unroll
      for (int t3 = 0; t3 < 3; ++t3) {
        const int qc = t3 * 8 + (cm >> 1);
#pragma unroll
        for (int j = 0; j < 8; ++j) {
          const unsigned uq = smem[(s0 + j) * W + qc];
          const unsigned uk = smem[(s0 + j) * W + 24 + qc];
          qf[t3][j] = (short)(half ? (uq >> 16) : (uq & 0xffffu));
          kf[t3][j] = (short)(half ? (uk >> 16) : (uk & 0xffffu));
        }
      }
#pragma unroll
      for (int mt = 0; mt < 3; ++mt)
#pragma unroll
        for (int nt = 0; nt < 3; ++nt)
          acc[mt][nt] = __builtin_amdgcn_mfma_f32_16x16x32_bf16(qf[mt], kf[nt], acc[mt][nt], 0, 0, 0);
    }
    if (tid < 192) {
      const int cu = (sch < 48) ? (sch >> 1) : 24 + ((sch - 48) >> 1);
      const int hf = sch & 1;
      const int sstart = shalf * 64;
#pragma unroll 4
      for (int s = 0; s < 64; ++s) {
        const unsigned u = smem[(sstart + s) * W + cu];
        const float v = bf2f((unsigned short)(hf ? (u >> 16) : (u & 0xffffu)));
        ssq_acc += v * v;
      }
    }
    __syncthreads();
  }

  // block reduce 4 wave-partials (reuse smem as floats), then atomics
  float* red = (float*)smem;
  const int col = lane & 15;
  const int rbase = (lane >> 4) * 4;
#pragma unroll
  for (int mt = 0; mt < 3; ++mt)
#pragma unroll
    for (int nt = 0; nt < 3; ++nt)
#pragma unroll
      for (int rg = 0; rg < 4; ++rg)
        red[wv * 2304 + (mt * 16 + rbase + rg) * 48 + nt * 16 + col] = acc[mt][nt][rg];
  __syncthreads();
  float* Gm = &G[(size_t)pair * 2304];
#pragma unroll
  for (int c = 0; c < 9; ++c) {
    const int cell = tid + (c << 8);
    const float s4 = red[cell] + red[2304 + cell] + red[4608 + cell] + red[6912 + cell];
    atomicAdd(&Gm[cell], s4);
  }
  if (tid < 192) {
    if (sch < 48) atomicAdd(&ssqq[img * 192 + h * 48 + sch], ssq_acc);
    else          atomicAdd(&ssqk[img * 192 + h * 48 + sch - 48], ssq_acc);
  }
}

// ---- softmax over d of G*temp/(|q||k|), one wave per (img,h,row) -----------
__global__ __launch_bounds__(64) void attn_softmax(const float* __restrict__ G,
                                                   const float* __restrict__ ssqq,
                                                   const float* __restrict__ ssqk,
                                                   const float* __restrict__ temp,
                                                   float* __restrict__ attn) {
  const int r = blockIdx.x;          // 0..47
  const int h = blockIdx.y & 3;
  const int img = blockIdx.y >> 2;
  const int lane = threadIdx.x;
  const size_t base = (size_t)(img * 4 + h) * 2304;
  const float t = temp[h];
  const float qn = ssqq[img * 192 + h * CH + r];
  float val = -1e30f;
  if (lane < 48) {
    const float kn = ssqk[img * 192 + h * CH + lane];
    val = G[base + r * 48 + lane] * t * rsqrtf(qn * kn);
  }
  float m = val;
#pragma unroll
  for (int off = 32; off; off >>= 1) m = fmaxf(m, __shfl_xor(m, off));
  const float e = (lane < 48) ? expf(val - m) : 0.f;
  float ssum = e;
#pragma unroll
  for (int off = 32; off; off >>= 1) ssum += __shfl_xor(ssum, off);
  if (lane < 48) attn[base + r * 48 + lane] = e / ssum;
}

// ---- W_eff^T[img][n][D] = sum_c' A[img][h(D)][c'][D%48] * Wp[48h+c'][n] ----
__global__ __launch_bounds__(256) void make_weff(const float* __restrict__ attn,
                                                 const float* __restrict__ wproj,
                                                 unsigned short* __restrict__ weh,
                                                 unsigned short* __restrict__ wel) {
  const int t = blockIdx.x * 256 + threadIdx.x;   // over 4*192*192
  const int img = t / 36864;
  const int r = t % 36864;
  const int n = r / 192;
  const int D = r % 192;
  const int h = D / 48, dd = D % 48;
  const float* A = &attn[(size_t)(img * 4 + h) * 2304 + dd];
  const float* Wp = &wproj[(size_t)(h * 48) * 192 + n];
  float acc = 0.f;
#pragma unroll
  for (int c = 0; c < 48; ++c) acc += A[c * 48] * Wp[c * 192];
  const unsigned short hb = f2bf(acc);
  weh[(size_t)img * 36864 + n * 192 + D] = hb;
  wel[(size_t)img * 36864 + n * 192 + D] = f2bf(acc - bf2f(hb));
}

}  // namespace

extern "C" void kernel_launch(void* const* d_in, const int* in_sizes, int n_in,
                              void* d_out, int out_size, void* d_ws, size_t ws_size,
                              hipStream_t stream) {
  const float* x      = (const float*)d_in[0];
  const float* w_qkv  = (const float*)d_in[1];
  const float* w_dw   = (const float*)d_in[2];
  const float* w_proj = (const float*)d_in[3];
  const float* temp   = (const float*)d_in[4];
  float* out = (float*)d_out;

  // NI images per pass. NI=4 ≈ 128 MB, fits the 256 MiB ws.
  auto layout_bytes = [](int NI) -> size_t {
    return (size_t)NI * HW * 576 * 2       // qkv bf16
         + (size_t)NI * HW * 384 * 2       // qk bf16
         + (size_t)NI * HW * 192 * 2       // vh (bf16)
         + 2 * 221184                      // wqh, wql
         + 153600                          // G, ssqq, ssqk (all 4 images)
         + 147456                          // attnb (all 4 images)
         + 2 * 294912;                     // weh, wel (all 4 images)
  };
  const int NI = (ws_size >= layout_bytes(4)) ? 4 : ((ws_size >= layout_bytes(2)) ? 2 : 1);
  const int npass = 4 / NI;
  const int npix = NI * HW;

  char* p = (char*)d_ws;
  unsigned short* qkv = (unsigned short*)p; p += (size_t)npix * 576 * 2;
  unsigned short* qk = (unsigned short*)p;  p += (size_t)npix * 384 * 2;
  unsigned short* vh = (unsigned short*)p;  p += (size_t)npix * 192 * 2;
  unsigned short* wqh = (unsigned short*)p; p += 221184;
  unsigned short* wql = (unsigned short*)p; p += 221184;
  float* G    = (float*)p;           p += 147456;   // 16 (img,h) pairs
  float* ssqq = (float*)p;           p += 3072;     // 4 img x 192
  float* ssqk = (float*)p;           p += 3072;
  float* attnb = (float*)p;          p += 147456;
  unsigned short* weh = (unsigned short*)p; p += 294912;
  unsigned short* wel = (unsigned short*)p;

  cvt_wqkv<<<432, 256, 0, stream>>>(w_qkv, wqh, wql);
  hipMemsetAsync(G, 0, 153600, stream);  // G+ssqq+ssqk, all 4 images, once

  for (int pass = 0; pass < npass; ++pass) {
    const float* xb = x + (size_t)pass * npix * K;
    float* outb = out + (size_t)pass * npix * C;
    float* Gp    = G + (size_t)pass * NI * 4 * 2304;
    float* sqp   = ssqq + (size_t)pass * NI * 192;
    float* skp   = ssqk + (size_t)pass * NI * 192;
    float* ap    = attnb + (size_t)pass * NI * 4 * 2304;
    unsigned short* wehp = weh + (size_t)pass * NI * 36864;
    unsigned short* welp = wel + (size_t)pass * NI * 36864;
    gemm_mfma<9, false, true, true><<<npix / 128, 256, 0, stream>>>(
        xb, wqh, wql, qkv);
    dwconv3x3_v5<<<npix * 144 / TY / 256, 256, 0, stream>>>(qkv, w_dw, qk, vh);
    gram48_v4<<<dim3(64, 4 * NI), 256, 0, stream>>>(qk, Gp, sqp, skp);
    attn_softmax<<<dim3(48, 4 * NI), 64, 0, stream>>>(Gp, sqp, skp, temp, ap);
    make_weff<<<NI * 144, 256, 0, stream>>>(ap, w_proj, wehp, welp);
    gemm_mfma<3, true, false, false><<<npix / 128, 256, 0, stream>>>(
        vh, wehp, welp, outb);
  }
}